// Round 1
// baseline (2100.693 us; speedup 1.0000x reference)
//
#include <hip/hip_runtime.h>
#include <math.h>

#define BATCH 4
#define CH    512
#define ICH   256
#define NPIX  4096   // 64*64

// ---------------------------------------------------------------------------
// Fused QKV 1x1-conv GEMM: out[M][N] = ReLU(W[M][C] @ F[C][N] + bias) (+ cc)
// grid (N/128, 8, B); block 256. y-block 0..1 -> Q, 2..3 -> K, 4..7 -> V.
// ---------------------------------------------------------------------------
__global__ __launch_bounds__(256)
void conv_qkv_kernel(const float* __restrict__ feat,
                     const float* __restrict__ qw, const float* __restrict__ qb,
                     const float* __restrict__ kw, const float* __restrict__ kb,
                     const float* __restrict__ vw, const float* __restrict__ vb,
                     const float* __restrict__ cw, const float* __restrict__ cb,
                     float* __restrict__ Qb, float* __restrict__ Kb,
                     float* __restrict__ Vb)
{
    __shared__ float Wt[16][132];   // W^T tile: [k][m], +4 pad
    __shared__ float Fs[16][132];   // F tile:   [k][n]

    const int tid = threadIdx.x;
    const int tx = tid & 15, ty = tid >> 4;
    const int b  = blockIdx.z;
    const int n0 = blockIdx.x * 128;
    const int yb = blockIdx.y;

    const float* Wp; const float* bp; float* outp; int m0; int use_cc;
    if (yb < 2)      { Wp = qw; bp = qb; outp = Qb + (size_t)b*ICH*NPIX; m0 = yb*128;     use_cc = 1; }
    else if (yb < 4) { Wp = kw; bp = kb; outp = Kb + (size_t)b*ICH*NPIX; m0 = (yb-2)*128; use_cc = 1; }
    else             { Wp = vw; bp = vb; outp = Vb + (size_t)b*CH*NPIX;  m0 = (yb-4)*128; use_cc = 0; }

    const float* F = feat + (size_t)b*CH*NPIX;

    float acc[8][8];
    #pragma unroll
    for (int i = 0; i < 8; i++)
        #pragma unroll
        for (int j = 0; j < 8; j++) acc[i][j] = 0.f;

    for (int k0 = 0; k0 < CH; k0 += 16) {
        #pragma unroll
        for (int t = 0; t < 8; t++) {                 // 128 m-rows x 16 k
            int idx = tid + t*256;
            int r = idx >> 4, kk = idx & 15;
            Wt[kk][r] = Wp[(size_t)(m0 + r)*CH + k0 + kk];
        }
        #pragma unroll
        for (int t = 0; t < 8; t++) {                 // 16 k x 128 n
            int idx = tid + t*256;
            int kk = idx >> 7, nn = idx & 127;
            Fs[kk][nn] = F[(size_t)(k0 + kk)*NPIX + n0 + nn];
        }
        __syncthreads();
        #pragma unroll
        for (int kk = 0; kk < 16; kk++) {
            float a[8], bb[8];
            #pragma unroll
            for (int i = 0; i < 8; i++) a[i]  = Wt[kk][ty*8 + i];
            #pragma unroll
            for (int j = 0; j < 8; j++) bb[j] = Fs[kk][tx*8 + j];
            #pragma unroll
            for (int i = 0; i < 8; i++)
                #pragma unroll
                for (int j = 0; j < 8; j++) acc[i][j] += a[i]*bb[j];
        }
        __syncthreads();
    }

    const float step = 2.0f / 63.0f;
    #pragma unroll
    for (int i = 0; i < 8; i++) {
        int o = m0 + ty*8 + i;
        float bias = bp[o];
        float cw0 = 0.f, cw1 = 0.f, cbv = 0.f;
        if (use_cc) { cw0 = cw[o*2+0]; cw1 = cw[o*2+1]; cbv = cb[o]; }
        #pragma unroll
        for (int j = 0; j < 8; j++) {
            int n = n0 + tx*8 + j;
            float v = fmaxf(acc[i][j] + bias, 0.f);
            if (use_cc) {
                int x = n & 63, y = n >> 6;
                float cx = -1.f + x*step;
                float cy = -1.f + y*step;
                v += fmaxf(cw0*cx + cw1*cy + cbv, 0.f);
            }
            outp[(size_t)o*NPIX + n] = v;
        }
    }
}

// ---------------------------------------------------------------------------
// a_sq[n] = sum_ic Q[ic][n]^2 ; b_sq from K. grid (N/256, B); block 256.
// ---------------------------------------------------------------------------
__global__ __launch_bounds__(256)
void sq_kernel(const float* __restrict__ Q, const float* __restrict__ K,
               float* __restrict__ a_sq, float* __restrict__ b_sq)
{
    int n = blockIdx.x*256 + threadIdx.x;
    int b = blockIdx.y;
    const float* Qp = Q + (size_t)b*ICH*NPIX + n;
    const float* Kp = K + (size_t)b*ICH*NPIX + n;
    float qa = 0.f, ka = 0.f;
    for (int ic = 0; ic < ICH; ic++) {
        float qv = Qp[(size_t)ic*NPIX]; qa += qv*qv;
        float kv = Kp[(size_t)ic*NPIX]; ka += kv*kv;
    }
    a_sq[b*NPIX + n] = qa;
    b_sq[b*NPIX + n] = ka;
}

// ---------------------------------------------------------------------------
// S~[n][m] = exp(-(a_sq[n] + b_sq[m] - 2 * Q[:,n].K[:,m])) ; one batch.
// grid (32, 32); block 256; tile 128x128, K=256.
// ---------------------------------------------------------------------------
__global__ __launch_bounds__(256)
void dots_exp_kernel(const float* __restrict__ Q, const float* __restrict__ K,
                     const float* __restrict__ asq, const float* __restrict__ bsq,
                     float* __restrict__ S)
{
    __shared__ float As[16][132];
    __shared__ float Bs[16][132];
    const int tid = threadIdx.x;
    const int tx = tid & 15, ty = tid >> 4;
    const int m0 = blockIdx.x * 128;
    const int n0 = blockIdx.y * 128;

    float acc[8][8];
    #pragma unroll
    for (int i = 0; i < 8; i++)
        #pragma unroll
        for (int j = 0; j < 8; j++) acc[i][j] = 0.f;

    for (int k0 = 0; k0 < ICH; k0 += 16) {
        #pragma unroll
        for (int t = 0; t < 8; t++) {
            int idx = tid + t*256;
            int kk = idx >> 7, nn = idx & 127;
            As[kk][nn] = Q[(size_t)(k0+kk)*NPIX + n0 + nn];
            Bs[kk][nn] = K[(size_t)(k0+kk)*NPIX + m0 + nn];
        }
        __syncthreads();
        #pragma unroll
        for (int kk = 0; kk < 16; kk++) {
            float a[8], bb[8];
            #pragma unroll
            for (int i = 0; i < 8; i++) a[i]  = As[kk][ty*8 + i];
            #pragma unroll
            for (int j = 0; j < 8; j++) bb[j] = Bs[kk][tx*8 + j];
            #pragma unroll
            for (int i = 0; i < 8; i++)
                #pragma unroll
                for (int j = 0; j < 8; j++) acc[i][j] += a[i]*bb[j];
        }
        __syncthreads();
    }

    float aq[8], bq[8];
    #pragma unroll
    for (int i = 0; i < 8; i++) aq[i] = asq[n0 + ty*8 + i];
    #pragma unroll
    for (int j = 0; j < 8; j++) bq[j] = bsq[m0 + tx*8 + j];
    #pragma unroll
    for (int i = 0; i < 8; i++) {
        size_t row = (size_t)(n0 + ty*8 + i)*NPIX + m0;
        #pragma unroll
        for (int j = 0; j < 8; j++) {
            float d = aq[i] + bq[j] - 2.f*acc[i][j];
            S[row + tx*8 + j] = __expf(-d);
        }
    }
}

// ---------------------------------------------------------------------------
// rinv[n] = 1 / (sum_m S[n][m] + 1e-14). grid (4096); block 256.
// ---------------------------------------------------------------------------
__global__ __launch_bounds__(256)
void rowsum_kernel(const float* __restrict__ S, float* __restrict__ rinv)
{
    const int n = blockIdx.x;
    const float4* row = (const float4*)(S + (size_t)n*NPIX);
    const int tid = threadIdx.x;
    float s = 0.f;
    #pragma unroll
    for (int k = 0; k < 4; k++) {
        float4 v = row[tid + k*256];
        s += v.x + v.y + v.z + v.w;
    }
    for (int off = 32; off > 0; off >>= 1) s += __shfl_down(s, off, 64);
    __shared__ float wsum[4];
    int lane = tid & 63, wv = tid >> 6;
    if (lane == 0) wsum[wv] = s;
    __syncthreads();
    if (tid == 0) {
        float t = wsum[0] + wsum[1] + wsum[2] + wsum[3];
        rinv[n] = 1.f / (t + 1e-14f);
    }
}

// ---------------------------------------------------------------------------
// out[c][m] = sum_n V[c][n]*rinv[n]*S[n][m] + feat[c][m]; one batch.
// grid (64, 8); block 256; tile 64(c) x 64(m), K=4096.
// ---------------------------------------------------------------------------
__global__ __launch_bounds__(256)
void pv_kernel(const float* __restrict__ V, const float* __restrict__ rinv,
               const float* __restrict__ S, const float* __restrict__ feat,
               float* __restrict__ out)
{
    __shared__ float Vs[16][68];   // [k][c], +4 pad
    __shared__ float Ss[16][68];   // [k][m]
    const int tid = threadIdx.x;
    const int tx = tid & 15, ty = tid >> 4;
    const int m0 = blockIdx.x * 64;
    const int c0 = blockIdx.y * 64;

    float acc[4][4];
    #pragma unroll
    for (int i = 0; i < 4; i++)
        #pragma unroll
        for (int j = 0; j < 4; j++) acc[i][j] = 0.f;

    for (int k0 = 0; k0 < NPIX; k0 += 16) {
        #pragma unroll
        for (int t = 0; t < 4; t++) {
            int idx = tid + t*256;
            { int r = idx >> 4, kk = idx & 15;     // V^T staging, scaled
              Vs[kk][r] = V[(size_t)(c0 + r)*NPIX + k0 + kk] * rinv[k0 + kk]; }
            { int kk = idx >> 6, mm = idx & 63;    // S rows
              Ss[kk][mm] = S[(size_t)(k0 + kk)*NPIX + m0 + mm]; }
        }
        __syncthreads();
        #pragma unroll
        for (int kk = 0; kk < 16; kk++) {
            float a[4], bb[4];
            #pragma unroll
            for (int i = 0; i < 4; i++) a[i]  = Vs[kk][ty*4 + i];
            #pragma unroll
            for (int j = 0; j < 4; j++) bb[j] = Ss[kk][tx*4 + j];
            #pragma unroll
            for (int i = 0; i < 4; i++)
                #pragma unroll
                for (int j = 0; j < 4; j++) acc[i][j] += a[i]*bb[j];
        }
        __syncthreads();
    }

    #pragma unroll
    for (int i = 0; i < 4; i++) {
        size_t base = (size_t)(c0 + ty*4 + i)*NPIX + m0;
        #pragma unroll
        for (int j = 0; j < 4; j++) {
            out[base + tx*4 + j] = acc[i][j] + feat[base + tx*4 + j];
        }
    }
}

// ---------------------------------------------------------------------------
extern "C" void kernel_launch(void* const* d_in, const int* in_sizes, int n_in,
                              void* d_out, int out_size, void* d_ws, size_t ws_size,
                              hipStream_t stream)
{
    const float* feat = (const float*)d_in[0];
    const float* qw   = (const float*)d_in[1];
    const float* qb   = (const float*)d_in[2];
    const float* kw   = (const float*)d_in[3];
    const float* kb   = (const float*)d_in[4];
    const float* vw   = (const float*)d_in[5];
    const float* vb   = (const float*)d_in[6];
    const float* cw   = (const float*)d_in[7];
    const float* cb   = (const float*)d_in[8];
    float* out = (float*)d_out;
    float* ws  = (float*)d_ws;

    // workspace layout (floats): total ~33.6M floats = 134.4 MB
    float* Qb   = ws;                                   // B*ICH*NPIX = 4.19M
    float* Kb   = Qb   + (size_t)BATCH*ICH*NPIX;        // 4.19M
    float* Vb   = Kb   + (size_t)BATCH*ICH*NPIX;        // B*CH*NPIX = 8.39M
    float* asq  = Vb   + (size_t)BATCH*CH*NPIX;         // B*NPIX
    float* bsq  = asq  + (size_t)BATCH*NPIX;
    float* rinv = bsq  + (size_t)BATCH*NPIX;
    float* S    = rinv + (size_t)BATCH*NPIX;            // NPIX*NPIX = 16.78M (per-batch reuse)

    conv_qkv_kernel<<<dim3(NPIX/128, 8, BATCH), 256, 0, stream>>>(
        feat, qw, qb, kw, kb, vw, vb, cw, cb, Qb, Kb, Vb);

    sq_kernel<<<dim3(NPIX/256, BATCH), 256, 0, stream>>>(Qb, Kb, asq, bsq);

    for (int b = 0; b < BATCH; b++) {
        dots_exp_kernel<<<dim3(NPIX/128, NPIX/128), 256, 0, stream>>>(
            Qb + (size_t)b*ICH*NPIX, Kb + (size_t)b*ICH*NPIX,
            asq + (size_t)b*NPIX, bsq + (size_t)b*NPIX, S);
        rowsum_kernel<<<dim3(NPIX), 256, 0, stream>>>(S, rinv + (size_t)b*NPIX);
        pv_kernel<<<dim3(NPIX/64, CH/64), 256, 0, stream>>>(
            Vb + (size_t)b*CH*NPIX, rinv + (size_t)b*NPIX, S,
            feat + (size_t)b*CH*NPIX, out + (size_t)b*CH*NPIX);
    }
}

// Round 2
// 684.446 us; speedup vs baseline: 3.0692x; 3.0692x over previous
//
#include <hip/hip_runtime.h>
#include <math.h>

#define BATCH 4
#define CH    512
#define ICH   256
#define NPIX  4096   // 64*64

typedef short short8 __attribute__((ext_vector_type(8)));
typedef float floatx4 __attribute__((ext_vector_type(4)));

#define BK   64
#define LDA  72    // BK + 8 bf16 pad: row stride 144B -> 2-way bank alias only (free)

static __device__ __forceinline__ unsigned short f2bf(float x) {
    union { float f; unsigned u; } v; v.f = x;
    unsigned r = (v.u + 0x7FFF + ((v.u >> 16) & 1)) >> 16;   // RNE
    return (unsigned short)r;
}
static __device__ __forceinline__ float bfhi(unsigned u) {   // high bf16 of a uint
    union { unsigned u; float f; } v; v.u = u & 0xFFFF0000u; return v.f;
}
static __device__ __forceinline__ float bflo(unsigned u) {   // low bf16 of a uint
    union { unsigned u; float f; } v; v.u = u << 16; return v.f;
}

// ---------------------------------------------------------------------------
// Fused QKV 1x1-conv GEMM (fp32 VALU). Writes Qt/Kt TRANSPOSED bf16 [n][ic]
// (K-contiguous for MFMA NT consumption) and V fp32 [c][n].
// grid (32, 8, B); block 256. y 0..1 -> Q, 2..3 -> K, 4..7 -> V.
// ---------------------------------------------------------------------------
__global__ __launch_bounds__(256)
void conv_qkv_kernel(const float* __restrict__ feat,
                     const float* __restrict__ qw, const float* __restrict__ qb,
                     const float* __restrict__ kw, const float* __restrict__ kb,
                     const float* __restrict__ vw, const float* __restrict__ vb,
                     const float* __restrict__ cw, const float* __restrict__ cb,
                     unsigned short* __restrict__ Qt, unsigned short* __restrict__ Kt,
                     float* __restrict__ Vb)
{
    __shared__ float Wt[16][132];
    __shared__ float Fs[16][132];

    const int tid = threadIdx.x;
    const int tx = tid & 15, ty = tid >> 4;
    const int b  = blockIdx.z;
    const int n0 = blockIdx.x * 128;
    const int yb = blockIdx.y;

    const float* Wp; const float* bp; int m0;
    unsigned short* Tt = nullptr; float* Vo = nullptr;
    if (yb < 2)      { Wp = qw; bp = qb; Tt = Qt + (size_t)b*NPIX*ICH; m0 = yb*128; }
    else if (yb < 4) { Wp = kw; bp = kb; Tt = Kt + (size_t)b*NPIX*ICH; m0 = (yb-2)*128; }
    else             { Wp = vw; bp = vb; Vo = Vb + (size_t)b*CH*NPIX;  m0 = (yb-4)*128; }

    const float* F = feat + (size_t)b*CH*NPIX;

    float acc[8][8];
    #pragma unroll
    for (int i = 0; i < 8; i++)
        #pragma unroll
        for (int j = 0; j < 8; j++) acc[i][j] = 0.f;

    for (int k0 = 0; k0 < CH; k0 += 16) {
        #pragma unroll
        for (int t = 0; t < 8; t++) {
            int idx = tid + t*256;
            int r = idx >> 4, kk = idx & 15;
            Wt[kk][r] = Wp[(size_t)(m0 + r)*CH + k0 + kk];
        }
        #pragma unroll
        for (int t = 0; t < 8; t++) {
            int idx = tid + t*256;
            int kk = idx >> 7, nn = idx & 127;
            Fs[kk][nn] = F[(size_t)(k0 + kk)*NPIX + n0 + nn];
        }
        __syncthreads();
        #pragma unroll
        for (int kk = 0; kk < 16; kk++) {
            float a[8], bb[8];
            #pragma unroll
            for (int i = 0; i < 8; i++) a[i]  = Wt[kk][ty*8 + i];
            #pragma unroll
            for (int j = 0; j < 8; j++) bb[j] = Fs[kk][tx*8 + j];
            #pragma unroll
            for (int i = 0; i < 8; i++)
                #pragma unroll
                for (int j = 0; j < 8; j++) acc[i][j] += a[i]*bb[j];
        }
        __syncthreads();
    }

    const float step = 2.0f / 63.0f;
    if (yb < 4) {
        // q/k + coord-conv, transposed bf16 write: Tt[n][ic], 16B per j
        #pragma unroll
        for (int j = 0; j < 8; j++) {
            int n = n0 + tx*8 + j;
            int x = n & 63, y = n >> 6;
            float cx = -1.f + x*step, cy = -1.f + y*step;
            unsigned short pk[8];
            #pragma unroll
            for (int i = 0; i < 8; i++) {
                int o = m0 + ty*8 + i;
                float v = fmaxf(acc[i][j] + bp[o], 0.f)
                        + fmaxf(cw[o*2+0]*cx + cw[o*2+1]*cy + cb[o], 0.f);
                pk[i] = f2bf(v);
            }
            *(uint4*)&Tt[(size_t)n*ICH + m0 + ty*8] = *(uint4*)pk;
        }
    } else {
        #pragma unroll
        for (int i = 0; i < 8; i++) {
            int o = m0 + ty*8 + i;
            float bias = bp[o];
            #pragma unroll
            for (int j = 0; j < 8; j++) {
                int n = n0 + tx*8 + j;
                Vo[(size_t)o*NPIX + n] = fmaxf(acc[i][j] + bias, 0.f);
            }
        }
    }
}

// ---------------------------------------------------------------------------
// asq[n] = sum_ic Qt[n][ic]^2 (bf16 inputs, fp32 accum); likewise bsq from Kt.
// grid (16, B); block 256 (one thread per pixel row).
// ---------------------------------------------------------------------------
__global__ __launch_bounds__(256)
void sqb_kernel(const unsigned short* __restrict__ Qt,
                const unsigned short* __restrict__ Kt,
                float* __restrict__ asq, float* __restrict__ bsq)
{
    int n = blockIdx.x*256 + threadIdx.x;
    int b = blockIdx.y;
    const uint4* q = (const uint4*)(Qt + ((size_t)b*NPIX + n)*ICH);
    const uint4* k = (const uint4*)(Kt + ((size_t)b*NPIX + n)*ICH);
    float qs = 0.f, ks = 0.f;
    #pragma unroll 8
    for (int i = 0; i < ICH/8; i++) {
        uint4 v = q[i];
        float a;
        a = bflo(v.x); qs += a*a;  a = bfhi(v.x); qs += a*a;
        a = bflo(v.y); qs += a*a;  a = bfhi(v.y); qs += a*a;
        a = bflo(v.z); qs += a*a;  a = bfhi(v.z); qs += a*a;
        a = bflo(v.w); qs += a*a;  a = bfhi(v.w); qs += a*a;
        uint4 w = k[i];
        a = bflo(w.x); ks += a*a;  a = bfhi(w.x); ks += a*a;
        a = bflo(w.y); ks += a*a;  a = bfhi(w.y); ks += a*a;
        a = bflo(w.z); ks += a*a;  a = bfhi(w.z); ks += a*a;
        a = bflo(w.w); ks += a*a;  a = bfhi(w.w); ks += a*a;
    }
    asq[b*NPIX + n] = qs;
    bsq[b*NPIX + n] = ks;
}

// ---------------------------------------------------------------------------
// St[m][n] = exp(-(asq[n]+bsq[m]-2*k_m.q_n)) (bf16 out) + column sums -> rsum[n].
// MFMA 16x16x32 bf16, tile 128x128, BK=64. A=Kt (rows m), B=Qt (cols n).
// grid (32, 32); block 256 (4 waves, 2x2 of 64x64).
// ---------------------------------------------------------------------------
__global__ __launch_bounds__(256)
void dots_mfma(const unsigned short* __restrict__ Kt,
               const unsigned short* __restrict__ Qt,
               const float* __restrict__ asq, const float* __restrict__ bsq,
               unsigned short* __restrict__ St, float* __restrict__ rsum)
{
    __shared__ unsigned short Al[128*LDA];
    __shared__ unsigned short Bl[128*LDA];
    const int tid = threadIdx.x;
    const int wid = tid >> 6, lane = tid & 63, quad = lane >> 4, lo = lane & 15;
    const int m0 = blockIdx.x * 128, n0 = blockIdx.y * 128;
    const int waveM = (wid >> 1) * 64, waveN = (wid & 1) * 64;

    floatx4 acc[4][4] = {};

    for (int k0 = 0; k0 < ICH; k0 += BK) {
        #pragma unroll
        for (int i = 0; i < 4; i++) {
            int idx = tid + i*256;
            int r = idx >> 3, c = (idx & 7) * 8;
            *(uint4*)&Al[r*LDA + c] = *(const uint4*)&Kt[(size_t)(m0+r)*ICH + k0 + c];
            *(uint4*)&Bl[r*LDA + c] = *(const uint4*)&Qt[(size_t)(n0+r)*ICH + k0 + c];
        }
        __syncthreads();
        #pragma unroll
        for (int ks = 0; ks < BK/32; ks++) {
            short8 a[4], bfr[4];
            #pragma unroll
            for (int im = 0; im < 4; im++)
                a[im] = *(const short8*)&Al[(waveM + im*16 + lo)*LDA + ks*32 + quad*8];
            #pragma unroll
            for (int in = 0; in < 4; in++)
                bfr[in] = *(const short8*)&Bl[(waveN + in*16 + lo)*LDA + ks*32 + quad*8];
            #pragma unroll
            for (int im = 0; im < 4; im++)
                #pragma unroll
                for (int in = 0; in < 4; in++)
                    acc[im][in] = __builtin_amdgcn_mfma_f32_16x16x32_bf16(
                        a[im], bfr[in], acc[im][in], 0, 0, 0);
        }
        __syncthreads();
    }

    // epilogue: exp(-D), bf16 store, fold column sums (over m) into rsum[n]
    #pragma unroll
    for (int in = 0; in < 4; in++) {
        int n = n0 + waveN + in*16 + lo;
        float aq = asq[n];
        float colsum = 0.f;
        #pragma unroll
        for (int im = 0; im < 4; im++) {
            int mb = m0 + waveM + im*16 + quad*4;
            #pragma unroll
            for (int r = 0; r < 4; r++) {
                float d = aq + bsq[mb + r] - 2.f*acc[im][in][r];
                float s = __expf(-d);
                colsum += s;
                St[(size_t)(mb + r)*NPIX + n] = f2bf(s);
            }
        }
        colsum += __shfl_xor(colsum, 16, 64);
        colsum += __shfl_xor(colsum, 32, 64);
        if (quad == 0) atomicAdd(&rsum[n], colsum);
    }
}

// ---------------------------------------------------------------------------
// V'[c][n] = bf16( V[c][n] / (rsum[n] + 1e-14) ).  grid 1024; block 256.
// ---------------------------------------------------------------------------
__global__ __launch_bounds__(256)
void vscale_kernel(const float* __restrict__ V, const float* __restrict__ rsum,
                   unsigned short* __restrict__ Vp)
{
    size_t base = ((size_t)blockIdx.x*256 + threadIdx.x) * 8;
    int n = (int)(base & (NPIX - 1));
    unsigned short pk[8];
    #pragma unroll
    for (int i = 0; i < 8; i++)
        pk[i] = f2bf(V[base + i] / (rsum[n + i] + 1e-14f));
    *(uint4*)&Vp[base] = *(uint4*)pk;
}

// ---------------------------------------------------------------------------
// out[c][m] = sum_n V'[c][n] * St[m][n] + feat[c][m].
// MFMA NT GEMM: A=V' (M=C rows c), B=St (N cols m), K=NPIX.
// tile 64(c) x 128(m), BK=64. grid (32, 8); block 256 (2x2 waves of 32x64).
// ---------------------------------------------------------------------------
__global__ __launch_bounds__(256)
void pv_mfma(const unsigned short* __restrict__ Vp,
             const unsigned short* __restrict__ St,
             const float* __restrict__ feat, float* __restrict__ out)
{
    __shared__ unsigned short Al[64*LDA];
    __shared__ unsigned short Bl[128*LDA];
    const int tid = threadIdx.x;
    const int wid = tid >> 6, lane = tid & 63, quad = lane >> 4, lo = lane & 15;
    const int m0 = blockIdx.x * 128, c0 = blockIdx.y * 64;
    const int waveC = (wid >> 1) * 32, waveM = (wid & 1) * 64;

    floatx4 acc[2][4] = {};

    for (int k0 = 0; k0 < NPIX; k0 += BK) {
        #pragma unroll
        for (int i = 0; i < 2; i++) {
            int idx = tid + i*256;
            int r = idx >> 3, c = (idx & 7) * 8;
            *(uint4*)&Al[r*LDA + c] = *(const uint4*)&Vp[(size_t)(c0+r)*NPIX + k0 + c];
        }
        #pragma unroll
        for (int i = 0; i < 4; i++) {
            int idx = tid + i*256;
            int r = idx >> 3, c = (idx & 7) * 8;
            *(uint4*)&Bl[r*LDA + c] = *(const uint4*)&St[(size_t)(m0+r)*NPIX + k0 + c];
        }
        __syncthreads();
        #pragma unroll
        for (int ks = 0; ks < BK/32; ks++) {
            short8 a[2], bfr[4];
            #pragma unroll
            for (int ia = 0; ia < 2; ia++)
                a[ia] = *(const short8*)&Al[(waveC + ia*16 + lo)*LDA + ks*32 + quad*8];
            #pragma unroll
            for (int ib = 0; ib < 4; ib++)
                bfr[ib] = *(const short8*)&Bl[(waveM + ib*16 + lo)*LDA + ks*32 + quad*8];
            #pragma unroll
            for (int ia = 0; ia < 2; ia++)
                #pragma unroll
                for (int ib = 0; ib < 4; ib++)
                    acc[ia][ib] = __builtin_amdgcn_mfma_f32_16x16x32_bf16(
                        a[ia], bfr[ib], acc[ia][ib], 0, 0, 0);
        }
        __syncthreads();
    }

    #pragma unroll
    for (int ia = 0; ia < 2; ia++) {
        int cb = c0 + waveC + ia*16 + quad*4;
        #pragma unroll
        for (int r = 0; r < 4; r++) {
            size_t rowbase = (size_t)(cb + r)*NPIX;
            #pragma unroll
            for (int ib = 0; ib < 4; ib++) {
                int m = m0 + waveM + ib*16 + lo;
                out[rowbase + m] = acc[ia][ib][r] + feat[rowbase + m];
            }
        }
    }
}

// ---------------------------------------------------------------------------
extern "C" void kernel_launch(void* const* d_in, const int* in_sizes, int n_in,
                              void* d_out, int out_size, void* d_ws, size_t ws_size,
                              hipStream_t stream)
{
    const float* feat = (const float*)d_in[0];
    const float* qw   = (const float*)d_in[1];
    const float* qb   = (const float*)d_in[2];
    const float* kw   = (const float*)d_in[3];
    const float* kb   = (const float*)d_in[4];
    const float* vw   = (const float*)d_in[5];
    const float* vb   = (const float*)d_in[6];
    const float* cw   = (const float*)d_in[7];
    const float* cb   = (const float*)d_in[8];
    float* out = (float*)d_out;
    char* ws = (char*)d_ws;

    // workspace layout (bytes), total ~100.9 MB
    unsigned short* Qt = (unsigned short*)ws;                 ws += (size_t)BATCH*NPIX*ICH*2;  // 8.39 MB
    unsigned short* Kt = (unsigned short*)ws;                 ws += (size_t)BATCH*NPIX*ICH*2;  // 8.39 MB
    float*          Vb = (float*)ws;                          ws += (size_t)BATCH*CH*NPIX*4;   // 33.55 MB
    unsigned short* Vp = (unsigned short*)ws;                 ws += (size_t)BATCH*CH*NPIX*2;   // 16.78 MB
    float*         asq = (float*)ws;                          ws += (size_t)BATCH*NPIX*4;
    float*         bsq = (float*)ws;                          ws += (size_t)BATCH*NPIX*4;
    float*        rsum = (float*)ws;                          ws += (size_t)BATCH*NPIX*4;
    unsigned short* St = (unsigned short*)ws;                                                   // 33.55 MB

    hipMemsetAsync(rsum, 0, (size_t)BATCH*NPIX*sizeof(float), stream);

    conv_qkv_kernel<<<dim3(NPIX/128, 8, BATCH), 256, 0, stream>>>(
        feat, qw, qb, kw, kb, vw, vb, cw, cb, Qt, Kt, Vb);

    sqb_kernel<<<dim3(NPIX/256, BATCH), 256, 0, stream>>>(Qt, Kt, asq, bsq);

    for (int b = 0; b < BATCH; b++) {
        dots_mfma<<<dim3(NPIX/128, NPIX/128), 256, 0, stream>>>(
            Kt + (size_t)b*NPIX*ICH, Qt + (size_t)b*NPIX*ICH,
            asq + (size_t)b*NPIX, bsq + (size_t)b*NPIX,
            St, rsum + (size_t)b*NPIX);
        vscale_kernel<<<dim3(CH*NPIX/(256*8)), 256, 0, stream>>>(
            Vb + (size_t)b*CH*NPIX, rsum + (size_t)b*NPIX, Vp + (size_t)b*CH*NPIX);
        pv_mfma<<<dim3(NPIX/128, CH/64), 256, 0, stream>>>(
            Vp + (size_t)b*CH*NPIX, St, feat + (size_t)b*CH*NPIX, out + (size_t)b*CH*NPIX);
    }
}

// Round 3
// 530.314 us; speedup vs baseline: 3.9612x; 1.2906x over previous
//
#include <hip/hip_runtime.h>
#include <math.h>

#define BATCH 4
#define CH    512
#define ICH   256
#define NPIX  4096   // 64*64

typedef short short8 __attribute__((ext_vector_type(8)));
typedef float floatx4 __attribute__((ext_vector_type(4)));

#define BK   64
#define LDA  72    // BK + 8 bf16 pad

static __device__ __forceinline__ unsigned short f2bf(float x) {
    union { float f; unsigned u; } v; v.f = x;
    unsigned r = (v.u + 0x7FFF + ((v.u >> 16) & 1)) >> 16;   // RNE
    return (unsigned short)r;
}
static __device__ __forceinline__ float bf2f(unsigned short u) {
    union { unsigned u; float f; } v; v.u = ((unsigned)u) << 16; return v.f;
}

// ---------------------------------------------------------------------------
// prep_w: qw/kw/vw fp32 -> Wb[1024][512] bf16 (rows: 0-255 Q, 256-511 K, 512-1023 V)
// ---------------------------------------------------------------------------
__global__ __launch_bounds__(256)
void prep_w(const float* __restrict__ qw, const float* __restrict__ kw,
            const float* __restrict__ vw, unsigned short* __restrict__ Wb)
{
    int i = (blockIdx.x*256 + threadIdx.x) * 4;
    const float* src;
    int off;
    if (i < 256*512)            { src = qw; off = i; }
    else if (i < 512*512)       { src = kw; off = i - 256*512; }
    else                        { src = vw; off = i - 512*512; }
    float4 f = *(const float4*)&src[off];
    unsigned short pk[4] = { f2bf(f.x), f2bf(f.y), f2bf(f.z), f2bf(f.w) };
    *(uint2*)&Wb[i] = *(uint2*)pk;
}

// ---------------------------------------------------------------------------
// prep_ft: feat [b][c][n] fp32 -> Fhi/Flo [b][n][c] bf16 (hi/lo split).
// 64x64 tiles via LDS (uint-packed, pad 65 -> conflict-free both phases).
// grid (NPIX/64, CH/64, B); block 256.
// ---------------------------------------------------------------------------
__global__ __launch_bounds__(256)
void prep_ft(const float* __restrict__ feat,
             unsigned short* __restrict__ Fhi, unsigned short* __restrict__ Flo)
{
    __shared__ unsigned S[64][65];
    const int t = threadIdx.x;
    const int n0 = blockIdx.x * 64, c0 = blockIdx.y * 64, b = blockIdx.z;

    #pragma unroll
    for (int rep = 0; rep < 4; rep++) {
        int cl = rep*16 + (t >> 4), col4 = (t & 15) * 4;
        float4 f = *(const float4*)&feat[((size_t)b*CH + c0 + cl)*NPIX + n0 + col4];
        float v[4] = { f.x, f.y, f.z, f.w };
        #pragma unroll
        for (int j = 0; j < 4; j++) {
            unsigned short hi = f2bf(v[j]);
            unsigned short lo = f2bf(v[j] - bf2f(hi));
            S[cl][col4 + j] = (unsigned)hi | ((unsigned)lo << 16);
        }
    }
    __syncthreads();
    #pragma unroll
    for (int rep = 0; rep < 4; rep++) {
        int nn = rep*16 + (t >> 4), cq = t & 15;
        unsigned short hi4[4], lo4[4];
        #pragma unroll
        for (int j = 0; j < 4; j++) {
            unsigned p = S[cq*4 + j][nn];
            hi4[j] = (unsigned short)(p & 0xFFFF);
            lo4[j] = (unsigned short)(p >> 16);
        }
        size_t base = ((size_t)b*NPIX + n0 + nn)*CH + c0 + cq*4;
        *(uint2*)&Fhi[base] = *(uint2*)hi4;
        *(uint2*)&Flo[base] = *(uint2*)lo4;
    }
}

// ---------------------------------------------------------------------------
// conv_mfma: fused QKV conv as bf16 MFMA GEMM, K=512, f = hi+lo planes.
// yb<2: Q (A=Ft rows n, B=Wq rows o) -> Qt[n][ic]
// yb<4: K likewise -> Kt[n][ic]
// yb>=4: V (A=Wv rows c, B=Ft rows n) -> Vt[c][n]
// grid (32, 8, B); block 256 (4 waves, 2x2 of 64x64).
// ---------------------------------------------------------------------------
__global__ __launch_bounds__(256)
void conv_mfma(const unsigned short* __restrict__ Fhi,
               const unsigned short* __restrict__ Flo,
               const unsigned short* __restrict__ Wb,
               const float* __restrict__ qb, const float* __restrict__ kb,
               const float* __restrict__ vb,
               const float* __restrict__ cw, const float* __restrict__ cb,
               unsigned short* __restrict__ Qt, unsigned short* __restrict__ Kt,
               unsigned short* __restrict__ Vt)
{
    __shared__ unsigned short L0[128*LDA];   // Fhi tile (rows n)
    __shared__ unsigned short L1[128*LDA];   // Flo tile (rows n)
    __shared__ unsigned short L2[128*LDA];   // W tile  (rows o)

    const int tid = threadIdx.x;
    const int wid = tid >> 6, lane = tid & 63, quad = lane >> 4, lo = lane & 15;
    const int n0 = blockIdx.x * 128;
    const int yb = blockIdx.y;
    const int bz = blockIdx.z;
    const int o_base = yb * 128;             // row into Wb (q:0-255, k:256-511, v:512-1023)
    const int waveA = (wid >> 1) * 64, waveB = (wid & 1) * 64;
    const int is_v = (yb >= 4);

    const size_t fbase = ((size_t)bz*NPIX + n0) * CH;

    floatx4 acc[4][4] = {};

    for (int k0 = 0; k0 < CH; k0 += BK) {
        #pragma unroll
        for (int i = 0; i < 4; i++) {
            int idx = tid + i*256;
            int r = idx >> 3, c8 = (idx & 7) * 8;
            *(uint4*)&L0[r*LDA + c8] = *(const uint4*)&Fhi[fbase + (size_t)r*CH + k0 + c8];
            *(uint4*)&L1[r*LDA + c8] = *(const uint4*)&Flo[fbase + (size_t)r*CH + k0 + c8];
            *(uint4*)&L2[r*LDA + c8] = *(const uint4*)&Wb[(size_t)(o_base + r)*CH + k0 + c8];
        }
        __syncthreads();
        if (!is_v) {
            #pragma unroll
            for (int ks = 0; ks < BK/32; ks++) {
                short8 ahi[4], alo[4], bw[4];
                #pragma unroll
                for (int i = 0; i < 4; i++) {
                    ahi[i] = *(const short8*)&L0[(waveA + i*16 + lo)*LDA + ks*32 + quad*8];
                    alo[i] = *(const short8*)&L1[(waveA + i*16 + lo)*LDA + ks*32 + quad*8];
                }
                #pragma unroll
                for (int j = 0; j < 4; j++)
                    bw[j] = *(const short8*)&L2[(waveB + j*16 + lo)*LDA + ks*32 + quad*8];
                #pragma unroll
                for (int i = 0; i < 4; i++)
                    #pragma unroll
                    for (int j = 0; j < 4; j++) {
                        acc[i][j] = __builtin_amdgcn_mfma_f32_16x16x32_bf16(ahi[i], bw[j], acc[i][j], 0, 0, 0);
                        acc[i][j] = __builtin_amdgcn_mfma_f32_16x16x32_bf16(alo[i], bw[j], acc[i][j], 0, 0, 0);
                    }
            }
        } else {
            #pragma unroll
            for (int ks = 0; ks < BK/32; ks++) {
                short8 aw[4], bhi[4], blo[4];
                #pragma unroll
                for (int i = 0; i < 4; i++)
                    aw[i] = *(const short8*)&L2[(waveA + i*16 + lo)*LDA + ks*32 + quad*8];
                #pragma unroll
                for (int j = 0; j < 4; j++) {
                    bhi[j] = *(const short8*)&L0[(waveB + j*16 + lo)*LDA + ks*32 + quad*8];
                    blo[j] = *(const short8*)&L1[(waveB + j*16 + lo)*LDA + ks*32 + quad*8];
                }
                #pragma unroll
                for (int i = 0; i < 4; i++)
                    #pragma unroll
                    for (int j = 0; j < 4; j++) {
                        acc[i][j] = __builtin_amdgcn_mfma_f32_16x16x32_bf16(aw[i], bhi[j], acc[i][j], 0, 0, 0);
                        acc[i][j] = __builtin_amdgcn_mfma_f32_16x16x32_bf16(aw[i], blo[j], acc[i][j], 0, 0, 0);
                    }
            }
        }
        __syncthreads();
    }

    const float step = 2.0f / 63.0f;
    if (!is_v) {
        // D[n][ic']: row(n) = waveA + ia*16 + quad*4 + r ; col = waveB + ib*16 + lo
        unsigned short* Tt = ((yb < 2) ? Qt : Kt) + (size_t)bz*NPIX*ICH;
        const float* bp = (yb < 2) ? qb : kb;
        const int ic_blk = (yb & 1) * 128 + waveB;
        #pragma unroll
        for (int ib = 0; ib < 4; ib++) {
            int ic = ic_blk + ib*16 + lo;
            float bias = bp[ic];
            float cw0 = cw[ic*2+0], cw1 = cw[ic*2+1], cbv = cb[ic];
            #pragma unroll
            for (int ia = 0; ia < 4; ia++) {
                int nb = n0 + waveA + ia*16 + quad*4;
                #pragma unroll
                for (int r = 0; r < 4; r++) {
                    int n = nb + r;
                    float cx = -1.f + (n & 63)*step;
                    float cy = -1.f + (n >> 6)*step;
                    float v = fmaxf(acc[ia][ib][r] + bias, 0.f)
                            + fmaxf(cw0*cx + cw1*cy + cbv, 0.f);
                    Tt[(size_t)n*ICH + ic] = f2bf(v);
                }
            }
        }
    } else {
        // D[c][n]: row(c) = waveA + ia*16 + quad*4 + r ; col(n) = waveB + ib*16 + lo
        const int c_blk = (yb - 4) * 128 + waveA;
        #pragma unroll
        for (int ia = 0; ia < 4; ia++) {
            int cb4 = c_blk + ia*16 + quad*4;
            #pragma unroll
            for (int r = 0; r < 4; r++) {
                int c = cb4 + r;
                float bias = vb[c];
                size_t rowbase = ((size_t)bz*CH + c)*NPIX + n0 + waveB;
                #pragma unroll
                for (int ib = 0; ib < 4; ib++)
                    Vt[rowbase + ib*16 + lo] = f2bf(fmaxf(acc[ia][ib][r] + bias, 0.f));
            }
        }
    }
}

// ---------------------------------------------------------------------------
// asq[n] = |q_n|^2, bsq[n] = |k_n|^2 from bf16 Qt/Kt [n][ic]. grid (16, B).
// ---------------------------------------------------------------------------
__global__ __launch_bounds__(256)
void sqb_kernel(const unsigned short* __restrict__ Qt,
                const unsigned short* __restrict__ Kt,
                float* __restrict__ asq, float* __restrict__ bsq)
{
    int n = blockIdx.x*256 + threadIdx.x;
    int b = blockIdx.y;
    const unsigned short* q = Qt + ((size_t)b*NPIX + n)*ICH;
    const unsigned short* k = Kt + ((size_t)b*NPIX + n)*ICH;
    float qs = 0.f, ks = 0.f;
    #pragma unroll 4
    for (int i = 0; i < ICH/8; i++) {
        uint4 v = *(const uint4*)&q[i*8];
        const unsigned short* s = (const unsigned short*)&v;
        #pragma unroll
        for (int j = 0; j < 8; j++) { float a = bf2f(s[j]); qs += a*a; }
        uint4 w = *(const uint4*)&k[i*8];
        const unsigned short* t = (const unsigned short*)&w;
        #pragma unroll
        for (int j = 0; j < 8; j++) { float a = bf2f(t[j]); ks += a*a; }
    }
    asq[b*NPIX + n] = qs;
    bsq[b*NPIX + n] = ks;
}

// ---------------------------------------------------------------------------
// St[m][n] = exp(-(asq[n]+bsq[m]-2*k_m.q_n)) bf16 + column sums -> rsum[n].
// grid (32, 32); block 256.
// ---------------------------------------------------------------------------
__global__ __launch_bounds__(256)
void dots_mfma(const unsigned short* __restrict__ Kt,
               const unsigned short* __restrict__ Qt,
               const float* __restrict__ asq, const float* __restrict__ bsq,
               unsigned short* __restrict__ St, float* __restrict__ rsum)
{
    __shared__ unsigned short Al[128*LDA];
    __shared__ unsigned short Bl[128*LDA];
    const int tid = threadIdx.x;
    const int wid = tid >> 6, lane = tid & 63, quad = lane >> 4, lo = lane & 15;
    const int m0 = blockIdx.x * 128, n0 = blockIdx.y * 128;
    const int waveM = (wid >> 1) * 64, waveN = (wid & 1) * 64;

    floatx4 acc[4][4] = {};

    for (int k0 = 0; k0 < ICH; k0 += BK) {
        #pragma unroll
        for (int i = 0; i < 4; i++) {
            int idx = tid + i*256;
            int r = idx >> 3, c = (idx & 7) * 8;
            *(uint4*)&Al[r*LDA + c] = *(const uint4*)&Kt[(size_t)(m0+r)*ICH + k0 + c];
            *(uint4*)&Bl[r*LDA + c] = *(const uint4*)&Qt[(size_t)(n0+r)*ICH + k0 + c];
        }
        __syncthreads();
        #pragma unroll
        for (int ks = 0; ks < BK/32; ks++) {
            short8 a[4], bfr[4];
            #pragma unroll
            for (int im = 0; im < 4; im++)
                a[im] = *(const short8*)&Al[(waveM + im*16 + lo)*LDA + ks*32 + quad*8];
            #pragma unroll
            for (int in = 0; in < 4; in++)
                bfr[in] = *(const short8*)&Bl[(waveN + in*16 + lo)*LDA + ks*32 + quad*8];
            #pragma unroll
            for (int im = 0; im < 4; im++)
                #pragma unroll
                for (int in = 0; in < 4; in++)
                    acc[im][in] = __builtin_amdgcn_mfma_f32_16x16x32_bf16(
                        a[im], bfr[in], acc[im][in], 0, 0, 0);
        }
        __syncthreads();
    }

    #pragma unroll
    for (int in = 0; in < 4; in++) {
        int n = n0 + waveN + in*16 + lo;
        float aq = asq[n];
        float colsum = 0.f;
        #pragma unroll
        for (int im = 0; im < 4; im++) {
            int mb = m0 + waveM + im*16 + quad*4;
            #pragma unroll
            for (int r = 0; r < 4; r++) {
                float d = aq + bsq[mb + r] - 2.f*acc[im][in][r];
                float s = __expf(-d);
                colsum += s;
                St[(size_t)(mb + r)*NPIX + n] = f2bf(s);
            }
        }
        colsum += __shfl_xor(colsum, 16, 64);
        colsum += __shfl_xor(colsum, 32, 64);
        if (quad == 0) atomicAdd(&rsum[n], colsum);
    }
}

// ---------------------------------------------------------------------------
// Vp[c][n] = bf16( Vt[c][n] / (rsum[n] + 1e-14) ). grid 1024; block 256.
// ---------------------------------------------------------------------------
__global__ __launch_bounds__(256)
void vscale_kernel(const unsigned short* __restrict__ Vt,
                   const float* __restrict__ rsum,
                   unsigned short* __restrict__ Vp)
{
    size_t base = ((size_t)blockIdx.x*256 + threadIdx.x) * 8;
    int n = (int)(base & (NPIX - 1));
    uint4 v = *(const uint4*)&Vt[base];
    const unsigned short* s = (const unsigned short*)&v;
    unsigned short pk[8];
    #pragma unroll
    for (int i = 0; i < 8; i++)
        pk[i] = f2bf(bf2f(s[i]) / (rsum[n + i] + 1e-14f));
    *(uint4*)&Vp[base] = *(uint4*)pk;
}

// ---------------------------------------------------------------------------
// out[c][m] = sum_n V'[c][n] * St[m][n] + feat[c][m]. grid (32, 8); block 256.
// ---------------------------------------------------------------------------
__global__ __launch_bounds__(256)
void pv_mfma(const unsigned short* __restrict__ Vp,
             const unsigned short* __restrict__ St,
             const float* __restrict__ feat, float* __restrict__ out)
{
    __shared__ unsigned short Al[64*LDA];
    __shared__ unsigned short Bl[128*LDA];
    const int tid = threadIdx.x;
    const int wid = tid >> 6, lane = tid & 63, quad = lane >> 4, lo = lane & 15;
    const int m0 = blockIdx.x * 128, c0 = blockIdx.y * 64;
    const int waveC = (wid >> 1) * 32, waveM = (wid & 1) * 64;

    floatx4 acc[2][4] = {};

    for (int k0 = 0; k0 < NPIX; k0 += BK) {
        #pragma unroll
        for (int i = 0; i < 2; i++) {
            int idx = tid + i*256;
            int r = idx >> 3, c = (idx & 7) * 8;
            *(uint4*)&Al[r*LDA + c] = *(const uint4*)&Vp[(size_t)(c0+r)*NPIX + k0 + c];
        }
        #pragma unroll
        for (int i = 0; i < 4; i++) {
            int idx = tid + i*256;
            int r = idx >> 3, c = (idx & 7) * 8;
            *(uint4*)&Bl[r*LDA + c] = *(const uint4*)&St[(size_t)(m0+r)*NPIX + k0 + c];
        }
        __syncthreads();
        #pragma unroll
        for (int ks = 0; ks < BK/32; ks++) {
            short8 a[2], bfr[4];
            #pragma unroll
            for (int ia = 0; ia < 2; ia++)
                a[ia] = *(const short8*)&Al[(waveC + ia*16 + lo)*LDA + ks*32 + quad*8];
            #pragma unroll
            for (int ib = 0; ib < 4; ib++)
                bfr[ib] = *(const short8*)&Bl[(waveM + ib*16 + lo)*LDA + ks*32 + quad*8];
            #pragma unroll
            for (int ia = 0; ia < 2; ia++)
                #pragma unroll
                for (int ib = 0; ib < 4; ib++)
                    acc[ia][ib] = __builtin_amdgcn_mfma_f32_16x16x32_bf16(
                        a[ia], bfr[ib], acc[ia][ib], 0, 0, 0);
        }
        __syncthreads();
    }

    #pragma unroll
    for (int ia = 0; ia < 2; ia++) {
        int cb = c0 + waveC + ia*16 + quad*4;
        #pragma unroll
        for (int r = 0; r < 4; r++) {
            size_t rowbase = (size_t)(cb + r)*NPIX;
            #pragma unroll
            for (int ib = 0; ib < 4; ib++) {
                int m = m0 + waveM + ib*16 + lo;
                out[rowbase + m] = acc[ia][ib][r] + feat[rowbase + m];
            }
        }
    }
}

// ---------------------------------------------------------------------------
extern "C" void kernel_launch(void* const* d_in, const int* in_sizes, int n_in,
                              void* d_out, int out_size, void* d_ws, size_t ws_size,
                              hipStream_t stream)
{
    const float* feat = (const float*)d_in[0];
    const float* qw   = (const float*)d_in[1];
    const float* qb   = (const float*)d_in[2];
    const float* kw   = (const float*)d_in[3];
    const float* kb   = (const float*)d_in[4];
    const float* vw   = (const float*)d_in[5];
    const float* vb   = (const float*)d_in[6];
    const float* cw   = (const float*)d_in[7];
    const float* cb   = (const float*)d_in[8];
    float* out = (float*)d_out;
    char* ws = (char*)d_ws;

    // workspace layout (~118.7 MB)
    unsigned short* Fhi = (unsigned short*)ws;  ws += (size_t)BATCH*NPIX*CH*2;   // 16.78 MB
    unsigned short* Flo = (unsigned short*)ws;  ws += (size_t)BATCH*NPIX*CH*2;   // 16.78 MB
    unsigned short* Wb  = (unsigned short*)ws;  ws += (size_t)1024*CH*2;         // 1.05 MB
    unsigned short* Qt  = (unsigned short*)ws;  ws += (size_t)BATCH*NPIX*ICH*2;  // 8.39 MB
    unsigned short* Kt  = (unsigned short*)ws;  ws += (size_t)BATCH*NPIX*ICH*2;  // 8.39 MB
    unsigned short* Vt  = (unsigned short*)ws;  ws += (size_t)BATCH*CH*NPIX*2;   // 16.78 MB
    unsigned short* Vp  = (unsigned short*)ws;  ws += (size_t)BATCH*CH*NPIX*2;   // 16.78 MB
    float*         asq  = (float*)ws;           ws += (size_t)BATCH*NPIX*4;
    float*         bsq  = (float*)ws;           ws += (size_t)BATCH*NPIX*4;
    float*         rsum = (float*)ws;           ws += (size_t)BATCH*NPIX*4;
    unsigned short* St  = (unsigned short*)ws;                                    // 33.55 MB

    hipMemsetAsync(rsum, 0, (size_t)BATCH*NPIX*sizeof(float), stream);

    prep_w<<<dim3(512), 256, 0, stream>>>(qw, kw, vw, Wb);
    prep_ft<<<dim3(NPIX/64, CH/64, BATCH), 256, 0, stream>>>(feat, Fhi, Flo);

    conv_mfma<<<dim3(NPIX/128, 8, BATCH), 256, 0, stream>>>(
        Fhi, Flo, Wb, qb, kb, vb, cw, cb, Qt, Kt, Vt);

    sqb_kernel<<<dim3(NPIX/256, BATCH), 256, 0, stream>>>(Qt, Kt, asq, bsq);

    for (int b = 0; b < BATCH; b++) {
        dots_mfma<<<dim3(NPIX/128, NPIX/128), 256, 0, stream>>>(
            Kt + (size_t)b*NPIX*ICH, Qt + (size_t)b*NPIX*ICH,
            asq + (size_t)b*NPIX, bsq + (size_t)b*NPIX,
            St, rsum + (size_t)b*NPIX);
        vscale_kernel<<<dim3(CH*NPIX/(256*8)), 256, 0, stream>>>(
            Vt + (size_t)b*CH*NPIX, rsum + (size_t)b*NPIX, Vp + (size_t)b*CH*NPIX);
        pv_mfma<<<dim3(NPIX/128, CH/64), 256, 0, stream>>>(
            Vp + (size_t)b*CH*NPIX, St, feat + (size_t)b*CH*NPIX, out + (size_t)b*CH*NPIX);
    }
}

// Round 4
// 477.927 us; speedup vs baseline: 4.3954x; 1.1096x over previous
//
#include <hip/hip_runtime.h>
#include <math.h>

#define BATCH 4
#define CH    512
#define ICH   256
#define NPIX  4096   // 64*64

typedef short short8 __attribute__((ext_vector_type(8)));
typedef float floatx4 __attribute__((ext_vector_type(4)));

#define BK   64
#define LDA  72    // BK + 8 bf16 pad

static __device__ __forceinline__ unsigned short f2bf(float x) {
    union { float f; unsigned u; } v; v.f = x;
    unsigned r = (v.u + 0x7FFF + ((v.u >> 16) & 1)) >> 16;   // RNE
    return (unsigned short)r;
}
static __device__ __forceinline__ float bf2f(unsigned short u) {
    union { unsigned u; float f; } v; v.u = ((unsigned)u) << 16; return v.f;
}

// ---------------------------------------------------------------------------
// prep_w: qw/kw/vw fp32 -> Wb[1024][512] bf16 (rows: 0-255 Q, 256-511 K, 512-1023 V)
// ---------------------------------------------------------------------------
__global__ __launch_bounds__(256)
void prep_w(const float* __restrict__ qw, const float* __restrict__ kw,
            const float* __restrict__ vw, unsigned short* __restrict__ Wb)
{
    int i = (blockIdx.x*256 + threadIdx.x) * 4;
    const float* src;
    int off;
    if (i < 256*512)            { src = qw; off = i; }
    else if (i < 512*512)       { src = kw; off = i - 256*512; }
    else                        { src = vw; off = i - 512*512; }
    float4 f = *(const float4*)&src[off];
    unsigned short pk[4] = { f2bf(f.x), f2bf(f.y), f2bf(f.z), f2bf(f.w) };
    *(uint2*)&Wb[i] = *(uint2*)pk;
}

// ---------------------------------------------------------------------------
// prep_ft: feat [b][c][n] fp32 -> Ft [b][n][c] bf16.
// 64x64 tiles via LDS (pad 65 -> conflict-free both phases).
// grid (NPIX/64, CH/64, B); block 256.
// ---------------------------------------------------------------------------
__global__ __launch_bounds__(256)
void prep_ft(const float* __restrict__ feat, unsigned short* __restrict__ Ft)
{
    __shared__ unsigned short S[64][65];
    const int t = threadIdx.x;
    const int n0 = blockIdx.x * 64, c0 = blockIdx.y * 64, b = blockIdx.z;

    #pragma unroll
    for (int rep = 0; rep < 4; rep++) {
        int cl = rep*16 + (t >> 4), col4 = (t & 15) * 4;
        float4 f = *(const float4*)&feat[((size_t)b*CH + c0 + cl)*NPIX + n0 + col4];
        S[cl][col4 + 0] = f2bf(f.x);
        S[cl][col4 + 1] = f2bf(f.y);
        S[cl][col4 + 2] = f2bf(f.z);
        S[cl][col4 + 3] = f2bf(f.w);
    }
    __syncthreads();
    #pragma unroll
    for (int rep = 0; rep < 4; rep++) {
        int nn = rep*16 + (t >> 4), cq = t & 15;
        unsigned short h4[4];
        #pragma unroll
        for (int j = 0; j < 4; j++) h4[j] = S[cq*4 + j][nn];
        *(uint2*)&Ft[((size_t)b*NPIX + n0 + nn)*CH + c0 + cq*4] = *(uint2*)h4;
    }
}

// ---------------------------------------------------------------------------
// conv_mfma: fused QKV conv as bf16 MFMA GEMM, K=512.
// yb<2: Q (A=Ft rows n, B=Wq rows o) -> Qt[n][ic]
// yb<4: K likewise -> Kt[n][ic]
// yb>=4: V (A=Wv rows c, B=Ft rows n) -> Vt[c][n]
// grid (32, 8, B); block 256 (4 waves, 2x2 of 64x64).
// ---------------------------------------------------------------------------
__global__ __launch_bounds__(256, 4)
void conv_mfma(const unsigned short* __restrict__ Ft,
               const unsigned short* __restrict__ Wb,
               const float* __restrict__ qb, const float* __restrict__ kb,
               const float* __restrict__ vb,
               const float* __restrict__ cw, const float* __restrict__ cb,
               unsigned short* __restrict__ Qt, unsigned short* __restrict__ Kt,
               unsigned short* __restrict__ Vt)
{
    __shared__ unsigned short L0[128*LDA];   // Ft tile (rows n)
    __shared__ unsigned short L2[128*LDA];   // W tile  (rows o)

    const int tid = threadIdx.x;
    const int wid = tid >> 6, lane = tid & 63, quad = lane >> 4, lo = lane & 15;
    const int n0 = blockIdx.x * 128;
    const int yb = blockIdx.y;
    const int bz = blockIdx.z;
    const int o_base = yb * 128;
    const int waveA = (wid >> 1) * 64, waveB = (wid & 1) * 64;
    const int is_v = (yb >= 4);

    const size_t fbase = ((size_t)bz*NPIX + n0) * CH;

    floatx4 acc[4][4] = {};

    for (int k0 = 0; k0 < CH; k0 += BK) {
        #pragma unroll
        for (int i = 0; i < 4; i++) {
            int idx = tid + i*256;
            int r = idx >> 3, c8 = (idx & 7) * 8;
            *(uint4*)&L0[r*LDA + c8] = *(const uint4*)&Ft[fbase + (size_t)r*CH + k0 + c8];
            *(uint4*)&L2[r*LDA + c8] = *(const uint4*)&Wb[(size_t)(o_base + r)*CH + k0 + c8];
        }
        __syncthreads();
        if (!is_v) {
            #pragma unroll
            for (int ks = 0; ks < BK/32; ks++) {
                short8 af[4], bw[4];
                #pragma unroll
                for (int i = 0; i < 4; i++)
                    af[i] = *(const short8*)&L0[(waveA + i*16 + lo)*LDA + ks*32 + quad*8];
                #pragma unroll
                for (int j = 0; j < 4; j++)
                    bw[j] = *(const short8*)&L2[(waveB + j*16 + lo)*LDA + ks*32 + quad*8];
                #pragma unroll
                for (int i = 0; i < 4; i++)
                    #pragma unroll
                    for (int j = 0; j < 4; j++)
                        acc[i][j] = __builtin_amdgcn_mfma_f32_16x16x32_bf16(af[i], bw[j], acc[i][j], 0, 0, 0);
            }
        } else {
            #pragma unroll
            for (int ks = 0; ks < BK/32; ks++) {
                short8 aw[4], bf[4];
                #pragma unroll
                for (int i = 0; i < 4; i++)
                    aw[i] = *(const short8*)&L2[(waveA + i*16 + lo)*LDA + ks*32 + quad*8];
                #pragma unroll
                for (int j = 0; j < 4; j++)
                    bf[j] = *(const short8*)&L0[(waveB + j*16 + lo)*LDA + ks*32 + quad*8];
                #pragma unroll
                for (int i = 0; i < 4; i++)
                    #pragma unroll
                    for (int j = 0; j < 4; j++)
                        acc[i][j] = __builtin_amdgcn_mfma_f32_16x16x32_bf16(aw[i], bf[j], acc[i][j], 0, 0, 0);
            }
        }
        __syncthreads();
    }

    const float step = 2.0f / 63.0f;
    if (!is_v) {
        unsigned short* Tt = ((yb < 2) ? Qt : Kt) + (size_t)bz*NPIX*ICH;
        const float* bp = (yb < 2) ? qb : kb;
        const int ic_blk = (yb & 1) * 128 + waveB;
        #pragma unroll
        for (int ib = 0; ib < 4; ib++) {
            int ic = ic_blk + ib*16 + lo;
            float bias = bp[ic];
            float cw0 = cw[ic*2+0], cw1 = cw[ic*2+1], cbv = cb[ic];
            #pragma unroll
            for (int ia = 0; ia < 4; ia++) {
                int nb = n0 + waveA + ia*16 + quad*4;
                #pragma unroll
                for (int r = 0; r < 4; r++) {
                    int n = nb + r;
                    float cx = -1.f + (n & 63)*step;
                    float cy = -1.f + (n >> 6)*step;
                    float v = fmaxf(acc[ia][ib][r] + bias, 0.f)
                            + fmaxf(cw0*cx + cw1*cy + cbv, 0.f);
                    Tt[(size_t)n*ICH + ic] = f2bf(v);
                }
            }
        }
    } else {
        const int c_blk = (yb - 4) * 128 + waveA;
        #pragma unroll
        for (int ia = 0; ia < 4; ia++) {
            int cb4 = c_blk + ia*16 + quad*4;
            #pragma unroll
            for (int r = 0; r < 4; r++) {
                int c = cb4 + r;
                float bias = vb[c];
                size_t rowbase = ((size_t)bz*CH + c)*NPIX + n0 + waveB;
                #pragma unroll
                for (int ib = 0; ib < 4; ib++)
                    Vt[rowbase + ib*16 + lo] = f2bf(fmaxf(acc[ia][ib][r] + bias, 0.f));
            }
        }
    }
}

// ---------------------------------------------------------------------------
// asq[n] = |q_n|^2, bsq[n] = |k_n|^2 from bf16 Qt/Kt [n][ic]. grid (16, B).
// ---------------------------------------------------------------------------
__global__ __launch_bounds__(256)
void sqb_kernel(const unsigned short* __restrict__ Qt,
                const unsigned short* __restrict__ Kt,
                float* __restrict__ asq, float* __restrict__ bsq)
{
    int n = blockIdx.x*256 + threadIdx.x;
    int b = blockIdx.y;
    const unsigned short* q = Qt + ((size_t)b*NPIX + n)*ICH;
    const unsigned short* k = Kt + ((size_t)b*NPIX + n)*ICH;
    float qs = 0.f, ks = 0.f;
    #pragma unroll 4
    for (int i = 0; i < ICH/8; i++) {
        uint4 v = *(const uint4*)&q[i*8];
        const unsigned short* s = (const unsigned short*)&v;
        #pragma unroll
        for (int j = 0; j < 8; j++) { float a = bf2f(s[j]); qs += a*a; }
        uint4 w = *(const uint4*)&k[i*8];
        const unsigned short* t = (const unsigned short*)&w;
        #pragma unroll
        for (int j = 0; j < 8; j++) { float a = bf2f(t[j]); ks += a*a; }
    }
    asq[b*NPIX + n] = qs;
    bsq[b*NPIX + n] = ks;
}

// ---------------------------------------------------------------------------
// St[bz][m][n] = exp(-(asq[n]+bsq[m]-2*k_m.q_n)) bf16 + col sums -> rsum[n].
// grid (32, 32, nb); block 256. Global batch = b0 + blockIdx.z.
// ---------------------------------------------------------------------------
__global__ __launch_bounds__(256, 4)
void dots_mfma(const unsigned short* __restrict__ Kt_,
               const unsigned short* __restrict__ Qt_,
               const float* __restrict__ asq_, const float* __restrict__ bsq_,
               unsigned short* __restrict__ St_, float* __restrict__ rsum_,
               int b0)
{
    __shared__ unsigned short Al[128*LDA];
    __shared__ unsigned short Bl[128*LDA];
    const int tid = threadIdx.x;
    const int wid = tid >> 6, lane = tid & 63, quad = lane >> 4, lo = lane & 15;
    const int m0 = blockIdx.x * 128, n0 = blockIdx.y * 128;
    const int bz = blockIdx.z, gb = b0 + bz;
    const int waveM = (wid >> 1) * 64, waveN = (wid & 1) * 64;

    const unsigned short* Kt = Kt_ + (size_t)gb*NPIX*ICH;
    const unsigned short* Qt = Qt_ + (size_t)gb*NPIX*ICH;
    const float* asq = asq_ + (size_t)gb*NPIX;
    const float* bsq = bsq_ + (size_t)gb*NPIX;
    unsigned short* St = St_ + (size_t)bz*NPIX*NPIX;
    float* rsum = rsum_ + (size_t)gb*NPIX;

    floatx4 acc[4][4] = {};

    for (int k0 = 0; k0 < ICH; k0 += BK) {
        #pragma unroll
        for (int i = 0; i < 4; i++) {
            int idx = tid + i*256;
            int r = idx >> 3, c = (idx & 7) * 8;
            *(uint4*)&Al[r*LDA + c] = *(const uint4*)&Kt[(size_t)(m0+r)*ICH + k0 + c];
            *(uint4*)&Bl[r*LDA + c] = *(const uint4*)&Qt[(size_t)(n0+r)*ICH + k0 + c];
        }
        __syncthreads();
        #pragma unroll
        for (int ks = 0; ks < BK/32; ks++) {
            short8 a[4], bfr[4];
            #pragma unroll
            for (int im = 0; im < 4; im++)
                a[im] = *(const short8*)&Al[(waveM + im*16 + lo)*LDA + ks*32 + quad*8];
            #pragma unroll
            for (int in = 0; in < 4; in++)
                bfr[in] = *(const short8*)&Bl[(waveN + in*16 + lo)*LDA + ks*32 + quad*8];
            #pragma unroll
            for (int im = 0; im < 4; im++)
                #pragma unroll
                for (int in = 0; in < 4; in++)
                    acc[im][in] = __builtin_amdgcn_mfma_f32_16x16x32_bf16(
                        a[im], bfr[in], acc[im][in], 0, 0, 0);
        }
        __syncthreads();
    }

    #pragma unroll
    for (int in = 0; in < 4; in++) {
        int n = n0 + waveN + in*16 + lo;
        float aq = asq[n];
        float colsum = 0.f;
        #pragma unroll
        for (int im = 0; im < 4; im++) {
            int mb = m0 + waveM + im*16 + quad*4;
            #pragma unroll
            for (int r = 0; r < 4; r++) {
                float d = aq + bsq[mb + r] - 2.f*acc[im][in][r];
                float s = __expf(-d);
                colsum += s;
                unsigned u = (unsigned)f2bf(s);
                unsigned partner = __shfl_xor(u, 1, 64);
                if ((lo & 1) == 0)
                    *(unsigned*)&St[(size_t)(mb + r)*NPIX + n] = u | (partner << 16);
            }
        }
        colsum += __shfl_xor(colsum, 16, 64);
        colsum += __shfl_xor(colsum, 32, 64);
        if (quad == 0) atomicAdd(&rsum[n], colsum);
    }
}

// ---------------------------------------------------------------------------
// Vp[c][n] = bf16( Vt[c][n] / (rsum[n] + 1e-14) ). grid (1024/nb..., nb).
// ---------------------------------------------------------------------------
__global__ __launch_bounds__(256)
void vscale_kernel(const unsigned short* __restrict__ Vt,
                   const float* __restrict__ rsum,
                   unsigned short* __restrict__ Vp, int b0)
{
    int gb = b0 + blockIdx.y;
    size_t base = (size_t)gb*CH*NPIX + ((size_t)blockIdx.x*256 + threadIdx.x) * 8;
    int n = (int)(base & (NPIX - 1));
    const float* rs = rsum + (size_t)gb*NPIX;
    uint4 v = *(const uint4*)&Vt[base];
    const unsigned short* s = (const unsigned short*)&v;
    unsigned short pk[8];
    #pragma unroll
    for (int i = 0; i < 8; i++)
        pk[i] = f2bf(bf2f(s[i]) / (rs[n + i] + 1e-14f));
    *(uint4*)&Vp[base] = *(uint4*)pk;
}

// ---------------------------------------------------------------------------
// out[c][m] = sum_n V'[c][n] * St[m][n] + feat[c][m].
// grid (32, 8, nb); block 256.
// ---------------------------------------------------------------------------
__global__ __launch_bounds__(256, 4)
void pv_mfma(const unsigned short* __restrict__ Vp_,
             const unsigned short* __restrict__ St_,
             const float* __restrict__ feat_, float* __restrict__ out_,
             int b0)
{
    __shared__ unsigned short Al[64*LDA];
    __shared__ unsigned short Bl[128*LDA];
    const int tid = threadIdx.x;
    const int wid = tid >> 6, lane = tid & 63, quad = lane >> 4, lo = lane & 15;
    const int m0 = blockIdx.x * 128, c0 = blockIdx.y * 64;
    const int bz = blockIdx.z, gb = b0 + bz;
    const int waveC = (wid >> 1) * 32, waveM = (wid & 1) * 64;

    const unsigned short* Vp = Vp_ + (size_t)gb*CH*NPIX;
    const unsigned short* St = St_ + (size_t)bz*NPIX*NPIX;
    const float* feat = feat_ + (size_t)gb*CH*NPIX;
    float* out = out_ + (size_t)gb*CH*NPIX;

    floatx4 acc[2][4] = {};

    for (int k0 = 0; k0 < NPIX; k0 += BK) {
        #pragma unroll
        for (int i = 0; i < 2; i++) {
            int idx = tid + i*256;
            int r = idx >> 3, c = (idx & 7) * 8;
            *(uint4*)&Al[r*LDA + c] = *(const uint4*)&Vp[(size_t)(c0+r)*NPIX + k0 + c];
        }
        #pragma unroll
        for (int i = 0; i < 4; i++) {
            int idx = tid + i*256;
            int r = idx >> 3, c = (idx & 7) * 8;
            *(uint4*)&Bl[r*LDA + c] = *(const uint4*)&St[(size_t)(m0+r)*NPIX + k0 + c];
        }
        __syncthreads();
        #pragma unroll
        for (int ks = 0; ks < BK/32; ks++) {
            short8 a[2], bfr[4];
            #pragma unroll
            for (int ia = 0; ia < 2; ia++)
                a[ia] = *(const short8*)&Al[(waveC + ia*16 + lo)*LDA + ks*32 + quad*8];
            #pragma unroll
            for (int ib = 0; ib < 4; ib++)
                bfr[ib] = *(const short8*)&Bl[(waveM + ib*16 + lo)*LDA + ks*32 + quad*8];
            #pragma unroll
            for (int ia = 0; ia < 2; ia++)
                #pragma unroll
                for (int ib = 0; ib < 4; ib++)
                    acc[ia][ib] = __builtin_amdgcn_mfma_f32_16x16x32_bf16(
                        a[ia], bfr[ib], acc[ia][ib], 0, 0, 0);
        }
        __syncthreads();
    }

    #pragma unroll
    for (int ia = 0; ia < 2; ia++) {
        int cb = c0 + waveC + ia*16 + quad*4;
        #pragma unroll
        for (int r = 0; r < 4; r++) {
            size_t rowbase = (size_t)(cb + r)*NPIX;
            #pragma unroll
            for (int ib = 0; ib < 4; ib++) {
                int m = m0 + waveM + ib*16 + lo;
                out[rowbase + m] = acc[ia][ib][r] + feat[rowbase + m];
            }
        }
    }
}

// ---------------------------------------------------------------------------
extern "C" void kernel_launch(void* const* d_in, const int* in_sizes, int n_in,
                              void* d_out, int out_size, void* d_ws, size_t ws_size,
                              hipStream_t stream)
{
    const float* feat = (const float*)d_in[0];
    const float* qw   = (const float*)d_in[1];
    const float* qb   = (const float*)d_in[2];
    const float* kw   = (const float*)d_in[3];
    const float* kb   = (const float*)d_in[4];
    const float* vw   = (const float*)d_in[5];
    const float* vb   = (const float*)d_in[6];
    const float* cw   = (const float*)d_in[7];
    const float* cb   = (const float*)d_in[8];
    float* out = (float*)d_out;
    char* ws = (char*)d_ws;
    char* ws0 = ws;

    unsigned short* Ft  = (unsigned short*)ws;  ws += (size_t)BATCH*NPIX*CH*2;   // 16.78 MB
    unsigned short* Wb  = (unsigned short*)ws;  ws += (size_t)1024*CH*2;         // 1.05 MB
    unsigned short* Qt  = (unsigned short*)ws;  ws += (size_t)BATCH*NPIX*ICH*2;  // 8.39 MB
    unsigned short* Kt  = (unsigned short*)ws;  ws += (size_t)BATCH*NPIX*ICH*2;  // 8.39 MB
    unsigned short* Vt  = (unsigned short*)ws;  ws += (size_t)BATCH*CH*NPIX*2;   // 16.78 MB
    unsigned short* Vp  = (unsigned short*)ws;  ws += (size_t)BATCH*CH*NPIX*2;   // 16.78 MB
    float*         asq  = (float*)ws;           ws += (size_t)BATCH*NPIX*4;
    float*         bsq  = (float*)ws;           ws += (size_t)BATCH*NPIX*4;
    float*         rsum = (float*)ws;           ws += (size_t)BATCH*NPIX*4;
    unsigned short* St  = (unsigned short*)ws;  // nb * 33.55 MB

    const size_t st1 = (size_t)NPIX*NPIX*2;
    const size_t fixed = (size_t)(ws - ws0);
    // all-batch St if workspace allows (needs ~203 MB total), else per-batch
    const int nb = (ws_size >= fixed + (size_t)BATCH*st1) ? BATCH : 1;

    hipMemsetAsync(rsum, 0, (size_t)BATCH*NPIX*sizeof(float), stream);

    prep_w<<<dim3(512), 256, 0, stream>>>(qw, kw, vw, Wb);
    prep_ft<<<dim3(NPIX/64, CH/64, BATCH), 256, 0, stream>>>(feat, Ft);

    conv_mfma<<<dim3(NPIX/128, 8, BATCH), 256, 0, stream>>>(
        Ft, Wb, qb, kb, vb, cw, cb, Qt, Kt, Vt);

    sqb_kernel<<<dim3(NPIX/256, BATCH), 256, 0, stream>>>(Qt, Kt, asq, bsq);

    for (int b0 = 0; b0 < BATCH; b0 += nb) {
        dots_mfma<<<dim3(NPIX/128, NPIX/128, nb), 256, 0, stream>>>(
            Kt, Qt, asq, bsq, St, rsum, b0);
        vscale_kernel<<<dim3(CH*NPIX/(256*8), nb), 256, 0, stream>>>(
            Vt, rsum, Vp, b0);
        pv_mfma<<<dim3(NPIX/128, CH/64, nb), 256, 0, stream>>>(
            Vp, St, feat, out, b0);
    }
}

// Round 5
// 443.574 us; speedup vs baseline: 4.7358x; 1.0774x over previous
//
#include <hip/hip_runtime.h>
#include <math.h>

#define BATCH 4
#define CH    512
#define ICH   256
#define NPIX  4096   // 64*64

typedef short short8 __attribute__((ext_vector_type(8)));
typedef float floatx4 __attribute__((ext_vector_type(4)));

#define BK   64
#define LDA  72    // BK + 8 bf16 pad

static __device__ __forceinline__ unsigned short f2bf(float x) {
    union { float f; unsigned u; } v; v.f = x;
    unsigned r = (v.u + 0x7FFF + ((v.u >> 16) & 1)) >> 16;   // RNE
    return (unsigned short)r;
}
static __device__ __forceinline__ float bf2f(unsigned short u) {
    union { unsigned u; float f; } v; v.u = ((unsigned)u) << 16; return v.f;
}

// ---------------------------------------------------------------------------
// prep_w: qw/kw/vw fp32 -> Wb[1024][512] bf16 (rows: 0-255 Q, 256-511 K, 512-1023 V)
// ---------------------------------------------------------------------------
__global__ __launch_bounds__(256)
void prep_w(const float* __restrict__ qw, const float* __restrict__ kw,
            const float* __restrict__ vw, unsigned short* __restrict__ Wb)
{
    int i = (blockIdx.x*256 + threadIdx.x) * 4;
    const float* src;
    int off;
    if (i < 256*512)            { src = qw; off = i; }
    else if (i < 512*512)       { src = kw; off = i - 256*512; }
    else                        { src = vw; off = i - 512*512; }
    float4 f = *(const float4*)&src[off];
    unsigned short pk[4] = { f2bf(f.x), f2bf(f.y), f2bf(f.z), f2bf(f.w) };
    *(uint2*)&Wb[i] = *(uint2*)pk;
}

// ---------------------------------------------------------------------------
// prep_ft: feat [b][c][n] fp32 -> Ft [b][n][c] bf16.
// 64x64 tiles via LDS (pad 65 -> conflict-free both phases).
// grid (NPIX/64, CH/64, B); block 256.
// ---------------------------------------------------------------------------
__global__ __launch_bounds__(256)
void prep_ft(const float* __restrict__ feat, unsigned short* __restrict__ Ft)
{
    __shared__ unsigned short S[64][65];
    const int t = threadIdx.x;
    const int n0 = blockIdx.x * 64, c0 = blockIdx.y * 64, b = blockIdx.z;

    #pragma unroll
    for (int rep = 0; rep < 4; rep++) {
        int cl = rep*16 + (t >> 4), col4 = (t & 15) * 4;
        float4 f = *(const float4*)&feat[((size_t)b*CH + c0 + cl)*NPIX + n0 + col4];
        S[cl][col4 + 0] = f2bf(f.x);
        S[cl][col4 + 1] = f2bf(f.y);
        S[cl][col4 + 2] = f2bf(f.z);
        S[cl][col4 + 3] = f2bf(f.w);
    }
    __syncthreads();
    #pragma unroll
    for (int rep = 0; rep < 4; rep++) {
        int nn = rep*16 + (t >> 4), cq = t & 15;
        unsigned short h4[4];
        #pragma unroll
        for (int j = 0; j < 4; j++) h4[j] = S[cq*4 + j][nn];
        *(uint2*)&Ft[((size_t)b*NPIX + n0 + nn)*CH + c0 + cq*4] = *(uint2*)h4;
    }
}

// ---------------------------------------------------------------------------
// conv_mfma: fused QKV conv as bf16 MFMA GEMM, K=512.
// yb<2: Q (A=Ft rows n, B=Wq rows o) -> Qt[n][ic]
// yb<4: K likewise -> Kt[n][ic]
// yb>=4: V (A=Wv rows c, B=Ft rows n) -> Vt[c][n]
// grid (32, 8, B); block 256 (4 waves, 2x2 of 64x64).
// NOTE: no min-waves bound — (256,4) caps unified VGPR+AGPR at 128 and
// spills the 64-AGPR accumulator to scratch (R4: 463 MB writes, 2.4x slower).
// ---------------------------------------------------------------------------
__global__ __launch_bounds__(256)
void conv_mfma(const unsigned short* __restrict__ Ft,
               const unsigned short* __restrict__ Wb,
               const float* __restrict__ qb, const float* __restrict__ kb,
               const float* __restrict__ vb,
               const float* __restrict__ cw, const float* __restrict__ cb,
               unsigned short* __restrict__ Qt, unsigned short* __restrict__ Kt,
               unsigned short* __restrict__ Vt)
{
    __shared__ unsigned short L0[128*LDA];   // Ft tile (rows n)
    __shared__ unsigned short L2[128*LDA];   // W tile  (rows o)

    const int tid = threadIdx.x;
    const int wid = tid >> 6, lane = tid & 63, quad = lane >> 4, lo = lane & 15;
    const int n0 = blockIdx.x * 128;
    const int yb = blockIdx.y;
    const int bz = blockIdx.z;
    const int o_base = yb * 128;
    const int waveA = (wid >> 1) * 64, waveB = (wid & 1) * 64;
    const int is_v = (yb >= 4);

    const size_t fbase = ((size_t)bz*NPIX + n0) * CH;

    floatx4 acc[4][4] = {};

    for (int k0 = 0; k0 < CH; k0 += BK) {
        #pragma unroll
        for (int i = 0; i < 4; i++) {
            int idx = tid + i*256;
            int r = idx >> 3, c8 = (idx & 7) * 8;
            *(uint4*)&L0[r*LDA + c8] = *(const uint4*)&Ft[fbase + (size_t)r*CH + k0 + c8];
            *(uint4*)&L2[r*LDA + c8] = *(const uint4*)&Wb[(size_t)(o_base + r)*CH + k0 + c8];
        }
        __syncthreads();
        if (!is_v) {
            #pragma unroll
            for (int ks = 0; ks < BK/32; ks++) {
                short8 af[4], bw[4];
                #pragma unroll
                for (int i = 0; i < 4; i++)
                    af[i] = *(const short8*)&L0[(waveA + i*16 + lo)*LDA + ks*32 + quad*8];
                #pragma unroll
                for (int j = 0; j < 4; j++)
                    bw[j] = *(const short8*)&L2[(waveB + j*16 + lo)*LDA + ks*32 + quad*8];
                #pragma unroll
                for (int i = 0; i < 4; i++)
                    #pragma unroll
                    for (int j = 0; j < 4; j++)
                        acc[i][j] = __builtin_amdgcn_mfma_f32_16x16x32_bf16(af[i], bw[j], acc[i][j], 0, 0, 0);
            }
        } else {
            #pragma unroll
            for (int ks = 0; ks < BK/32; ks++) {
                short8 aw[4], bf[4];
                #pragma unroll
                for (int i = 0; i < 4; i++)
                    aw[i] = *(const short8*)&L2[(waveA + i*16 + lo)*LDA + ks*32 + quad*8];
                #pragma unroll
                for (int j = 0; j < 4; j++)
                    bf[j] = *(const short8*)&L0[(waveB + j*16 + lo)*LDA + ks*32 + quad*8];
                #pragma unroll
                for (int i = 0; i < 4; i++)
                    #pragma unroll
                    for (int j = 0; j < 4; j++)
                        acc[i][j] = __builtin_amdgcn_mfma_f32_16x16x32_bf16(aw[i], bf[j], acc[i][j], 0, 0, 0);
            }
        }
        __syncthreads();
    }

    const float step = 2.0f / 63.0f;
    if (!is_v) {
        unsigned short* Tt = ((yb < 2) ? Qt : Kt) + (size_t)bz*NPIX*ICH;
        const float* bp = (yb < 2) ? qb : kb;
        const int ic_blk = (yb & 1) * 128 + waveB;
        #pragma unroll
        for (int ib = 0; ib < 4; ib++) {
            int ic = ic_blk + ib*16 + lo;
            float bias = bp[ic];
            float cw0 = cw[ic*2+0], cw1 = cw[ic*2+1], cbv = cb[ic];
            #pragma unroll
            for (int ia = 0; ia < 4; ia++) {
                int nb = n0 + waveA + ia*16 + quad*4;
                #pragma unroll
                for (int r = 0; r < 4; r++) {
                    int n = nb + r;
                    float cx = -1.f + (n & 63)*step;
                    float cy = -1.f + (n >> 6)*step;
                    float v = fmaxf(acc[ia][ib][r] + bias, 0.f)
                            + fmaxf(cw0*cx + cw1*cy + cbv, 0.f);
                    Tt[(size_t)n*ICH + ic] = f2bf(v);
                }
            }
        }
    } else {
        const int c_blk = (yb - 4) * 128 + waveA;
        #pragma unroll
        for (int ia = 0; ia < 4; ia++) {
            int cb4 = c_blk + ia*16 + quad*4;
            #pragma unroll
            for (int r = 0; r < 4; r++) {
                int c = cb4 + r;
                float bias = vb[c];
                size_t rowbase = ((size_t)bz*CH + c)*NPIX + n0 + waveB;
                #pragma unroll
                for (int ib = 0; ib < 4; ib++)
                    Vt[rowbase + ib*16 + lo] = f2bf(fmaxf(acc[ia][ib][r] + bias, 0.f));
            }
        }
    }
}

// ---------------------------------------------------------------------------
// asq[n] = |q_n|^2, bsq[n] = |k_n|^2 from bf16 Qt/Kt [n][ic]. grid (16, B).
// ---------------------------------------------------------------------------
__global__ __launch_bounds__(256)
void sqb_kernel(const unsigned short* __restrict__ Qt,
                const unsigned short* __restrict__ Kt,
                float* __restrict__ asq, float* __restrict__ bsq)
{
    int n = blockIdx.x*256 + threadIdx.x;
    int b = blockIdx.y;
    const unsigned short* q = Qt + ((size_t)b*NPIX + n)*ICH;
    const unsigned short* k = Kt + ((size_t)b*NPIX + n)*ICH;
    float qs = 0.f, ks = 0.f;
    #pragma unroll 4
    for (int i = 0; i < ICH/8; i++) {
        uint4 v = *(const uint4*)&q[i*8];
        const unsigned short* s = (const unsigned short*)&v;
        #pragma unroll
        for (int j = 0; j < 8; j++) { float a = bf2f(s[j]); qs += a*a; }
        uint4 w = *(const uint4*)&k[i*8];
        const unsigned short* t = (const unsigned short*)&w;
        #pragma unroll
        for (int j = 0; j < 8; j++) { float a = bf2f(t[j]); ks += a*a; }
    }
    asq[b*NPIX + n] = qs;
    bsq[b*NPIX + n] = ks;
}

// ---------------------------------------------------------------------------
// St[bz][m][n] = exp(-(asq[n]+bsq[m]-2*k_m.q_n)) bf16 + col sums -> rsum[n].
// grid (32, 32, nb); block 256. Global batch = b0 + blockIdx.z.
// ---------------------------------------------------------------------------
__global__ __launch_bounds__(256)
void dots_mfma(const unsigned short* __restrict__ Kt_,
               const unsigned short* __restrict__ Qt_,
               const float* __restrict__ asq_, const float* __restrict__ bsq_,
               unsigned short* __restrict__ St_, float* __restrict__ rsum_,
               int b0)
{
    __shared__ unsigned short Al[128*LDA];
    __shared__ unsigned short Bl[128*LDA];
    const int tid = threadIdx.x;
    const int wid = tid >> 6, lane = tid & 63, quad = lane >> 4, lo = lane & 15;
    const int m0 = blockIdx.x * 128, n0 = blockIdx.y * 128;
    const int bz = blockIdx.z, gb = b0 + bz;
    const int waveM = (wid >> 1) * 64, waveN = (wid & 1) * 64;

    const unsigned short* Kt = Kt_ + (size_t)gb*NPIX*ICH;
    const unsigned short* Qt = Qt_ + (size_t)gb*NPIX*ICH;
    const float* asq = asq_ + (size_t)gb*NPIX;
    const float* bsq = bsq_ + (size_t)gb*NPIX;
    unsigned short* St = St_ + (size_t)bz*NPIX*NPIX;
    float* rsum = rsum_ + (size_t)gb*NPIX;

    floatx4 acc[4][4] = {};

    for (int k0 = 0; k0 < ICH; k0 += BK) {
        #pragma unroll
        for (int i = 0; i < 4; i++) {
            int idx = tid + i*256;
            int r = idx >> 3, c = (idx & 7) * 8;
            *(uint4*)&Al[r*LDA + c] = *(const uint4*)&Kt[(size_t)(m0+r)*ICH + k0 + c];
            *(uint4*)&Bl[r*LDA + c] = *(const uint4*)&Qt[(size_t)(n0+r)*ICH + k0 + c];
        }
        __syncthreads();
        #pragma unroll
        for (int ks = 0; ks < BK/32; ks++) {
            short8 a[4], bfr[4];
            #pragma unroll
            for (int im = 0; im < 4; im++)
                a[im] = *(const short8*)&Al[(waveM + im*16 + lo)*LDA + ks*32 + quad*8];
            #pragma unroll
            for (int in = 0; in < 4; in++)
                bfr[in] = *(const short8*)&Bl[(waveN + in*16 + lo)*LDA + ks*32 + quad*8];
            #pragma unroll
            for (int im = 0; im < 4; im++)
                #pragma unroll
                for (int in = 0; in < 4; in++)
                    acc[im][in] = __builtin_amdgcn_mfma_f32_16x16x32_bf16(
                        a[im], bfr[in], acc[im][in], 0, 0, 0);
        }
        __syncthreads();
    }

    #pragma unroll
    for (int in = 0; in < 4; in++) {
        int n = n0 + waveN + in*16 + lo;
        float aq = asq[n];
        float colsum = 0.f;
        #pragma unroll
        for (int im = 0; im < 4; im++) {
            int mb = m0 + waveM + im*16 + quad*4;
            #pragma unroll
            for (int r = 0; r < 4; r++) {
                float d = aq + bsq[mb + r] - 2.f*acc[im][in][r];
                float s = __expf(-d);
                colsum += s;
                unsigned u = (unsigned)f2bf(s);
                unsigned partner = __shfl_xor(u, 1, 64);
                if ((lo & 1) == 0)
                    *(unsigned*)&St[(size_t)(mb + r)*NPIX + n] = u | (partner << 16);
            }
        }
        colsum += __shfl_xor(colsum, 16, 64);
        colsum += __shfl_xor(colsum, 32, 64);
        if (quad == 0) atomicAdd(&rsum[n], colsum);
    }
}

// ---------------------------------------------------------------------------
// Vp[c][n] = bf16( Vt[c][n] / (rsum[n] + 1e-14) ). grid (1024/nb..., nb).
// ---------------------------------------------------------------------------
__global__ __launch_bounds__(256)
void vscale_kernel(const unsigned short* __restrict__ Vt,
                   const float* __restrict__ rsum,
                   unsigned short* __restrict__ Vp, int b0)
{
    int gb = b0 + blockIdx.y;
    size_t base = (size_t)gb*CH*NPIX + ((size_t)blockIdx.x*256 + threadIdx.x) * 8;
    int n = (int)(base & (NPIX - 1));
    const float* rs = rsum + (size_t)gb*NPIX;
    uint4 v = *(const uint4*)&Vt[base];
    const unsigned short* s = (const unsigned short*)&v;
    unsigned short pk[8];
    #pragma unroll
    for (int i = 0; i < 8; i++)
        pk[i] = f2bf(bf2f(s[i]) / (rs[n + i] + 1e-14f));
    *(uint4*)&Vp[base] = *(uint4*)pk;
}

// ---------------------------------------------------------------------------
// out[c][m] = sum_n V'[c][n] * St[m][n] + feat[c][m].
// grid (32, 8, nb); block 256.
// ---------------------------------------------------------------------------
__global__ __launch_bounds__(256)
void pv_mfma(const unsigned short* __restrict__ Vp_,
             const unsigned short* __restrict__ St_,
             const float* __restrict__ feat_, float* __restrict__ out_,
             int b0)
{
    __shared__ unsigned short Al[64*LDA];
    __shared__ unsigned short Bl[128*LDA];
    const int tid = threadIdx.x;
    const int wid = tid >> 6, lane = tid & 63, quad = lane >> 4, lo = lane & 15;
    const int m0 = blockIdx.x * 128, c0 = blockIdx.y * 64;
    const int bz = blockIdx.z, gb = b0 + bz;
    const int waveC = (wid >> 1) * 32, waveM = (wid & 1) * 64;

    const unsigned short* Vp = Vp_ + (size_t)gb*CH*NPIX;
    const unsigned short* St = St_ + (size_t)bz*NPIX*NPIX;
    const float* feat = feat_ + (size_t)gb*CH*NPIX;
    float* out = out_ + (size_t)gb*CH*NPIX;

    floatx4 acc[2][4] = {};

    for (int k0 = 0; k0 < NPIX; k0 += BK) {
        #pragma unroll
        for (int i = 0; i < 2; i++) {
            int idx = tid + i*256;
            int r = idx >> 3, c = (idx & 7) * 8;
            *(uint4*)&Al[r*LDA + c] = *(const uint4*)&Vp[(size_t)(c0+r)*NPIX + k0 + c];
        }
        #pragma unroll
        for (int i = 0; i < 4; i++) {
            int idx = tid + i*256;
            int r = idx >> 3, c = (idx & 7) * 8;
            *(uint4*)&Bl[r*LDA + c] = *(const uint4*)&St[(size_t)(m0+r)*NPIX + k0 + c];
        }
        __syncthreads();
        #pragma unroll
        for (int ks = 0; ks < BK/32; ks++) {
            short8 a[2], bfr[4];
            #pragma unroll
            for (int ia = 0; ia < 2; ia++)
                a[ia] = *(const short8*)&Al[(waveC + ia*16 + lo)*LDA + ks*32 + quad*8];
            #pragma unroll
            for (int ib = 0; ib < 4; ib++)
                bfr[ib] = *(const short8*)&Bl[(waveM + ib*16 + lo)*LDA + ks*32 + quad*8];
            #pragma unroll
            for (int ia = 0; ia < 2; ia++)
                #pragma unroll
                for (int ib = 0; ib < 4; ib++)
                    acc[ia][ib] = __builtin_amdgcn_mfma_f32_16x16x32_bf16(
                        a[ia], bfr[ib], acc[ia][ib], 0, 0, 0);
        }
        __syncthreads();
    }

    #pragma unroll
    for (int ia = 0; ia < 2; ia++) {
        int cb = c0 + waveC + ia*16 + quad*4;
        #pragma unroll
        for (int r = 0; r < 4; r++) {
            size_t rowbase = (size_t)(cb + r)*NPIX;
            #pragma unroll
            for (int ib = 0; ib < 4; ib++) {
                int m = m0 + waveM + ib*16 + lo;
                out[rowbase + m] = acc[ia][ib][r] + feat[rowbase + m];
            }
        }
    }
}

// ---------------------------------------------------------------------------
extern "C" void kernel_launch(void* const* d_in, const int* in_sizes, int n_in,
                              void* d_out, int out_size, void* d_ws, size_t ws_size,
                              hipStream_t stream)
{
    const float* feat = (const float*)d_in[0];
    const float* qw   = (const float*)d_in[1];
    const float* qb   = (const float*)d_in[2];
    const float* kw   = (const float*)d_in[3];
    const float* kb   = (const float*)d_in[4];
    const float* vw   = (const float*)d_in[5];
    const float* vb   = (const float*)d_in[6];
    const float* cw   = (const float*)d_in[7];
    const float* cb   = (const float*)d_in[8];
    float* out = (float*)d_out;
    char* ws = (char*)d_ws;
    char* ws0 = ws;

    unsigned short* Ft  = (unsigned short*)ws;  ws += (size_t)BATCH*NPIX*CH*2;   // 16.78 MB
    unsigned short* Wb  = (unsigned short*)ws;  ws += (size_t)1024*CH*2;         // 1.05 MB
    unsigned short* Qt  = (unsigned short*)ws;  ws += (size_t)BATCH*NPIX*ICH*2;  // 8.39 MB
    unsigned short* Kt  = (unsigned short*)ws;  ws += (size_t)BATCH*NPIX*ICH*2;  // 8.39 MB
    unsigned short* Vt  = (unsigned short*)ws;  ws += (size_t)BATCH*CH*NPIX*2;   // 16.78 MB
    unsigned short* Vp  = (unsigned short*)ws;  ws += (size_t)BATCH*CH*NPIX*2;   // 16.78 MB
    float*         asq  = (float*)ws;           ws += (size_t)BATCH*NPIX*4;
    float*         bsq  = (float*)ws;           ws += (size_t)BATCH*NPIX*4;
    float*         rsum = (float*)ws;           ws += (size_t)BATCH*NPIX*4;
    unsigned short* St  = (unsigned short*)ws;  // nb * 33.55 MB

    const size_t st1 = (size_t)NPIX*NPIX*2;
    const size_t fixed = (size_t)(ws - ws0);
    // all-batch St if workspace allows (needs ~203 MB total), else per-batch
    const int nb = (ws_size >= fixed + (size_t)BATCH*st1) ? BATCH : 1;

    hipMemsetAsync(rsum, 0, (size_t)BATCH*NPIX*sizeof(float), stream);

    prep_w<<<dim3(512), 256, 0, stream>>>(qw, kw, vw, Wb);
    prep_ft<<<dim3(NPIX/64, CH/64, BATCH), 256, 0, stream>>>(feat, Ft);

    conv_mfma<<<dim3(NPIX/128, 8, BATCH), 256, 0, stream>>>(
        Ft, Wb, qb, kb, vb, cw, cb, Qt, Kt, Vt);

    sqb_kernel<<<dim3(NPIX/256, BATCH), 256, 0, stream>>>(Qt, Kt, asq, bsq);

    for (int b0 = 0; b0 < BATCH; b0 += nb) {
        dots_mfma<<<dim3(NPIX/128, NPIX/128, nb), 256, 0, stream>>>(
            Kt, Qt, asq, bsq, St, rsum, b0);
        vscale_kernel<<<dim3(CH*NPIX/(256*8), nb), 256, 0, stream>>>(
            Vt, rsum, Vp, b0);
        pv_mfma<<<dim3(NPIX/128, CH/64, nb), 256, 0, stream>>>(
            Vp, St, feat, out, b0);
    }
}

// Round 6
// 385.708 us; speedup vs baseline: 5.4463x; 1.1500x over previous
//
#include <hip/hip_runtime.h>
#include <math.h>

#define BATCH 4
#define CH    512
#define ICH   256
#define NPIX  4096   // 64*64

typedef short short8 __attribute__((ext_vector_type(8)));
typedef float floatx4 __attribute__((ext_vector_type(4)));

#define BK   64
#define LDA  72    // BK + 8 bf16 pad
#define TS   136   // S-tile LDS stride (272B: 16B-aligned rows, quads 2-way max)

static __device__ __forceinline__ unsigned short f2bf(float x) {
    union { float f; unsigned u; } v; v.f = x;
    unsigned r = (v.u + 0x7FFF + ((v.u >> 16) & 1)) >> 16;   // RNE
    return (unsigned short)r;
}
static __device__ __forceinline__ float bf2f(unsigned short u) {
    union { unsigned u; float f; } v; v.u = ((unsigned)u) << 16; return v.f;
}

// ---------------------------------------------------------------------------
// prep_w: qw/kw/vw fp32 -> Wb[1024][512] bf16 (rows: 0-255 Q, 256-511 K, 512-1023 V)
// ---------------------------------------------------------------------------
__global__ __launch_bounds__(256)
void prep_w(const float* __restrict__ qw, const float* __restrict__ kw,
            const float* __restrict__ vw, unsigned short* __restrict__ Wb)
{
    int i = (blockIdx.x*256 + threadIdx.x) * 4;
    const float* src;
    int off;
    if (i < 256*512)            { src = qw; off = i; }
    else if (i < 512*512)       { src = kw; off = i - 256*512; }
    else                        { src = vw; off = i - 512*512; }
    float4 f = *(const float4*)&src[off];
    unsigned short pk[4] = { f2bf(f.x), f2bf(f.y), f2bf(f.z), f2bf(f.w) };
    *(uint2*)&Wb[i] = *(uint2*)pk;
}

// ---------------------------------------------------------------------------
// prep_ft: feat [b][c][n] fp32 -> Ft [b][n][c] bf16.
// grid (NPIX/64, CH/64, B); block 256.
// ---------------------------------------------------------------------------
__global__ __launch_bounds__(256)
void prep_ft(const float* __restrict__ feat, unsigned short* __restrict__ Ft)
{
    __shared__ unsigned short S[64][65];
    const int t = threadIdx.x;
    const int n0 = blockIdx.x * 64, c0 = blockIdx.y * 64, b = blockIdx.z;

    #pragma unroll
    for (int rep = 0; rep < 4; rep++) {
        int cl = rep*16 + (t >> 4), col4 = (t & 15) * 4;
        float4 f = *(const float4*)&feat[((size_t)b*CH + c0 + cl)*NPIX + n0 + col4];
        S[cl][col4 + 0] = f2bf(f.x);
        S[cl][col4 + 1] = f2bf(f.y);
        S[cl][col4 + 2] = f2bf(f.z);
        S[cl][col4 + 3] = f2bf(f.w);
    }
    __syncthreads();
    #pragma unroll
    for (int rep = 0; rep < 4; rep++) {
        int nn = rep*16 + (t >> 4), cq = t & 15;
        unsigned short h4[4];
        #pragma unroll
        for (int j = 0; j < 4; j++) h4[j] = S[cq*4 + j][nn];
        *(uint2*)&Ft[((size_t)b*NPIX + n0 + nn)*CH + c0 + cq*4] = *(uint2*)h4;
    }
}

// ---------------------------------------------------------------------------
// conv_mfma: fused QKV conv as bf16 MFMA GEMM, K=512.
// NOTE: no min-waves bound — (256,4) spills the 64-AGPR accumulator (R4).
// ---------------------------------------------------------------------------
__global__ __launch_bounds__(256)
void conv_mfma(const unsigned short* __restrict__ Ft,
               const unsigned short* __restrict__ Wb,
               const float* __restrict__ qb, const float* __restrict__ kb,
               const float* __restrict__ vb,
               const float* __restrict__ cw, const float* __restrict__ cb,
               unsigned short* __restrict__ Qt, unsigned short* __restrict__ Kt,
               unsigned short* __restrict__ Vt)
{
    __shared__ unsigned short L0[128*LDA];   // Ft tile (rows n)
    __shared__ unsigned short L2[128*LDA];   // W tile  (rows o)

    const int tid = threadIdx.x;
    const int wid = tid >> 6, lane = tid & 63, quad = lane >> 4, lo = lane & 15;
    const int n0 = blockIdx.x * 128;
    const int yb = blockIdx.y;
    const int bz = blockIdx.z;
    const int o_base = yb * 128;
    const int waveA = (wid >> 1) * 64, waveB = (wid & 1) * 64;
    const int is_v = (yb >= 4);

    const size_t fbase = ((size_t)bz*NPIX + n0) * CH;

    floatx4 acc[4][4] = {};

    for (int k0 = 0; k0 < CH; k0 += BK) {
        #pragma unroll
        for (int i = 0; i < 4; i++) {
            int idx = tid + i*256;
            int r = idx >> 3, c8 = (idx & 7) * 8;
            *(uint4*)&L0[r*LDA + c8] = *(const uint4*)&Ft[fbase + (size_t)r*CH + k0 + c8];
            *(uint4*)&L2[r*LDA + c8] = *(const uint4*)&Wb[(size_t)(o_base + r)*CH + k0 + c8];
        }
        __syncthreads();
        if (!is_v) {
            #pragma unroll
            for (int ks = 0; ks < BK/32; ks++) {
                short8 af[4], bw[4];
                #pragma unroll
                for (int i = 0; i < 4; i++)
                    af[i] = *(const short8*)&L0[(waveA + i*16 + lo)*LDA + ks*32 + quad*8];
                #pragma unroll
                for (int j = 0; j < 4; j++)
                    bw[j] = *(const short8*)&L2[(waveB + j*16 + lo)*LDA + ks*32 + quad*8];
                #pragma unroll
                for (int i = 0; i < 4; i++)
                    #pragma unroll
                    for (int j = 0; j < 4; j++)
                        acc[i][j] = __builtin_amdgcn_mfma_f32_16x16x32_bf16(af[i], bw[j], acc[i][j], 0, 0, 0);
            }
        } else {
            #pragma unroll
            for (int ks = 0; ks < BK/32; ks++) {
                short8 aw[4], bf[4];
                #pragma unroll
                for (int i = 0; i < 4; i++)
                    aw[i] = *(const short8*)&L2[(waveA + i*16 + lo)*LDA + ks*32 + quad*8];
                #pragma unroll
                for (int j = 0; j < 4; j++)
                    bf[j] = *(const short8*)&L0[(waveB + j*16 + lo)*LDA + ks*32 + quad*8];
                #pragma unroll
                for (int i = 0; i < 4; i++)
                    #pragma unroll
                    for (int j = 0; j < 4; j++)
                        acc[i][j] = __builtin_amdgcn_mfma_f32_16x16x32_bf16(aw[i], bf[j], acc[i][j], 0, 0, 0);
            }
        }
        __syncthreads();
    }

    const float step = 2.0f / 63.0f;
    if (!is_v) {
        unsigned short* Tt = ((yb < 2) ? Qt : Kt) + (size_t)bz*NPIX*ICH;
        const float* bp = (yb < 2) ? qb : kb;
        const int ic_blk = (yb & 1) * 128 + waveB;
        #pragma unroll
        for (int ib = 0; ib < 4; ib++) {
            int ic = ic_blk + ib*16 + lo;
            float bias = bp[ic];
            float cw0 = cw[ic*2+0], cw1 = cw[ic*2+1], cbv = cb[ic];
            #pragma unroll
            for (int ia = 0; ia < 4; ia++) {
                int nb = n0 + waveA + ia*16 + quad*4;
                #pragma unroll
                for (int r = 0; r < 4; r++) {
                    int n = nb + r;
                    float cx = -1.f + (n & 63)*step;
                    float cy = -1.f + (n >> 6)*step;
                    float v = fmaxf(acc[ia][ib][r] + bias, 0.f)
                            + fmaxf(cw0*cx + cw1*cy + cbv, 0.f);
                    Tt[(size_t)n*ICH + ic] = f2bf(v);
                }
            }
        }
    } else {
        const int c_blk = (yb - 4) * 128 + waveA;
        #pragma unroll
        for (int ia = 0; ia < 4; ia++) {
            int cb4 = c_blk + ia*16 + quad*4;
            #pragma unroll
            for (int r = 0; r < 4; r++) {
                int c = cb4 + r;
                float bias = vb[c];
                size_t rowbase = ((size_t)bz*CH + c)*NPIX + n0 + waveB;
                #pragma unroll
                for (int ib = 0; ib < 4; ib++)
                    Vt[rowbase + ib*16 + lo] = f2bf(fmaxf(acc[ia][ib][r] + bias, 0.f));
            }
        }
    }
}

// ---------------------------------------------------------------------------
// asq[n] = |q_n|^2, bsq[n] = |k_n|^2 from bf16 Qt/Kt [n][ic]. grid (16, B).
// ---------------------------------------------------------------------------
__global__ __launch_bounds__(256)
void sqb_kernel(const unsigned short* __restrict__ Qt,
                const unsigned short* __restrict__ Kt,
                float* __restrict__ asq, float* __restrict__ bsq)
{
    int n = blockIdx.x*256 + threadIdx.x;
    int b = blockIdx.y;
    const unsigned short* q = Qt + ((size_t)b*NPIX + n)*ICH;
    const unsigned short* k = Kt + ((size_t)b*NPIX + n)*ICH;
    float qs = 0.f, ks = 0.f;
    #pragma unroll 4
    for (int i = 0; i < ICH/8; i++) {
        uint4 v = *(const uint4*)&q[i*8];
        const unsigned short* s = (const unsigned short*)&v;
        #pragma unroll
        for (int j = 0; j < 8; j++) { float a = bf2f(s[j]); qs += a*a; }
        uint4 w = *(const uint4*)&k[i*8];
        const unsigned short* t = (const unsigned short*)&w;
        #pragma unroll
        for (int j = 0; j < 8; j++) { float a = bf2f(t[j]); ks += a*a; }
    }
    asq[b*NPIX + n] = qs;
    bsq[b*NPIX + n] = ks;
}

// ---------------------------------------------------------------------------
// St[bz][m][n] = exp(-(asq[n]+bsq[m]-2*k_m.q_n)) bf16 + col sums -> rsum[n].
// Epilogue stages the 128x128 S-tile in LDS (reusing Al/Bl), then stores
// fully-coalesced 256B rows -> every HBM line written once, complete
// (R5: scattered 32B chunks caused 2.17x write amplification, 291 vs 134 MB).
// grid (32, 32, nb); block 256.
// ---------------------------------------------------------------------------
__global__ __launch_bounds__(256)
void dots_mfma(const unsigned short* __restrict__ Kt_,
               const unsigned short* __restrict__ Qt_,
               const float* __restrict__ asq_, const float* __restrict__ bsq_,
               unsigned short* __restrict__ St_, float* __restrict__ rsum_,
               int b0)
{
    __shared__ unsigned short SH[2*128*LDA];   // Al | Bl, reused as S-tile
    unsigned short* Al = SH;
    unsigned short* Bl = SH + 128*LDA;

    const int tid = threadIdx.x;
    const int wid = tid >> 6, lane = tid & 63, quad = lane >> 4, lo = lane & 15;
    const int m0 = blockIdx.x * 128, n0 = blockIdx.y * 128;
    const int bz = blockIdx.z, gb = b0 + bz;
    const int waveM = (wid >> 1) * 64, waveN = (wid & 1) * 64;

    const unsigned short* Kt = Kt_ + (size_t)gb*NPIX*ICH;
    const unsigned short* Qt = Qt_ + (size_t)gb*NPIX*ICH;
    const float* asq = asq_ + (size_t)gb*NPIX;
    const float* bsq = bsq_ + (size_t)gb*NPIX;
    unsigned short* St = St_ + (size_t)bz*NPIX*NPIX;
    float* rsum = rsum_ + (size_t)gb*NPIX;

    floatx4 acc[4][4] = {};

    for (int k0 = 0; k0 < ICH; k0 += BK) {
        #pragma unroll
        for (int i = 0; i < 4; i++) {
            int idx = tid + i*256;
            int r = idx >> 3, c = (idx & 7) * 8;
            *(uint4*)&Al[r*LDA + c] = *(const uint4*)&Kt[(size_t)(m0+r)*ICH + k0 + c];
            *(uint4*)&Bl[r*LDA + c] = *(const uint4*)&Qt[(size_t)(n0+r)*ICH + k0 + c];
        }
        __syncthreads();
        #pragma unroll
        for (int ks = 0; ks < BK/32; ks++) {
            short8 a[4], bfr[4];
            #pragma unroll
            for (int im = 0; im < 4; im++)
                a[im] = *(const short8*)&Al[(waveM + im*16 + lo)*LDA + ks*32 + quad*8];
            #pragma unroll
            for (int in = 0; in < 4; in++)
                bfr[in] = *(const short8*)&Bl[(waveN + in*16 + lo)*LDA + ks*32 + quad*8];
            #pragma unroll
            for (int im = 0; im < 4; im++)
                #pragma unroll
                for (int in = 0; in < 4; in++)
                    acc[im][in] = __builtin_amdgcn_mfma_f32_16x16x32_bf16(
                        a[im], bfr[in], acc[im][in], 0, 0, 0);
        }
        __syncthreads();
    }

    // epilogue phase 1: exp(-D) -> LDS tile (pair-packed dword writes), colsums
    #pragma unroll
    for (int in = 0; in < 4; in++) {
        int nl = waveN + in*16 + lo;
        float aq = asq[n0 + nl];
        float colsum = 0.f;
        #pragma unroll
        for (int im = 0; im < 4; im++) {
            int mb = waveM + im*16 + quad*4;
            #pragma unroll
            for (int r = 0; r < 4; r++) {
                float d = aq + bsq[m0 + mb + r] - 2.f*acc[im][in][r];
                float s = __expf(-d);
                colsum += s;
                unsigned u = (unsigned)f2bf(s);
                unsigned partner = __shfl_xor(u, 1, 64);
                if ((lo & 1) == 0)
                    *(unsigned*)&SH[(mb + r)*TS + nl] = u | (partner << 16);
            }
        }
        colsum += __shfl_xor(colsum, 16, 64);
        colsum += __shfl_xor(colsum, 32, 64);
        if (quad == 0) atomicAdd(&rsum[n0 + nl], colsum);
    }
    __syncthreads();

    // epilogue phase 2: coalesced store, 256B contiguous per row
    #pragma unroll
    for (int it = 0; it < 8; it++) {
        int f = it*256 + tid;
        int row = f >> 4, col = (f & 15) * 8;
        uint4 v = *(const uint4*)&SH[row*TS + col];
        *(uint4*)&St[(size_t)(m0 + row)*NPIX + n0 + col] = v;
    }
}

// ---------------------------------------------------------------------------
// Vp[c][n] = bf16( Vt[c][n] / (rsum[n] + 1e-14) ). grid (1024/nb..., nb).
// ---------------------------------------------------------------------------
__global__ __launch_bounds__(256)
void vscale_kernel(const unsigned short* __restrict__ Vt,
                   const float* __restrict__ rsum,
                   unsigned short* __restrict__ Vp, int b0)
{
    int gb = b0 + blockIdx.y;
    size_t base = (size_t)gb*CH*NPIX + ((size_t)blockIdx.x*256 + threadIdx.x) * 8;
    int n = (int)(base & (NPIX - 1));
    const float* rs = rsum + (size_t)gb*NPIX;
    uint4 v = *(const uint4*)&Vt[base];
    const unsigned short* s = (const unsigned short*)&v;
    unsigned short pk[8];
    #pragma unroll
    for (int i = 0; i < 8; i++)
        pk[i] = f2bf(bf2f(s[i]) / (rs[n + i] + 1e-14f));
    *(uint4*)&Vp[base] = *(uint4*)pk;
}

// ---------------------------------------------------------------------------
// out[c][m] = sum_n V'[c][n] * St[m][n] + feat[c][m]. grid (32, 8, nb).
// ---------------------------------------------------------------------------
__global__ __launch_bounds__(256)
void pv_mfma(const unsigned short* __restrict__ Vp_,
             const unsigned short* __restrict__ St_,
             const float* __restrict__ feat_, float* __restrict__ out_,
             int b0)
{
    __shared__ unsigned short Al[64*LDA];
    __shared__ unsigned short Bl[128*LDA];
    const int tid = threadIdx.x;
    const int wid = tid >> 6, lane = tid & 63, quad = lane >> 4, lo = lane & 15;
    const int m0 = blockIdx.x * 128, c0 = blockIdx.y * 64;
    const int bz = blockIdx.z, gb = b0 + bz;
    const int waveC = (wid >> 1) * 32, waveM = (wid & 1) * 64;

    const unsigned short* Vp = Vp_ + (size_t)gb*CH*NPIX;
    const unsigned short* St = St_ + (size_t)bz*NPIX*NPIX;
    const float* feat = feat_ + (size_t)gb*CH*NPIX;
    float* out = out_ + (size_t)gb*CH*NPIX;

    floatx4 acc[2][4] = {};

    for (int k0 = 0; k0 < NPIX; k0 += BK) {
        #pragma unroll
        for (int i = 0; i < 2; i++) {
            int idx = tid + i*256;
            int r = idx >> 3, c = (idx & 7) * 8;
            *(uint4*)&Al[r*LDA + c] = *(const uint4*)&Vp[(size_t)(c0+r)*NPIX + k0 + c];
        }
        #pragma unroll
        for (int i = 0; i < 4; i++) {
            int idx = tid + i*256;
            int r = idx >> 3, c = (idx & 7) * 8;
            *(uint4*)&Bl[r*LDA + c] = *(const uint4*)&St[(size_t)(m0+r)*NPIX + k0 + c];
        }
        __syncthreads();
        #pragma unroll
        for (int ks = 0; ks < BK/32; ks++) {
            short8 a[2], bfr[4];
            #pragma unroll
            for (int ia = 0; ia < 2; ia++)
                a[ia] = *(const short8*)&Al[(waveC + ia*16 + lo)*LDA + ks*32 + quad*8];
            #pragma unroll
            for (int ib = 0; ib < 4; ib++)
                bfr[ib] = *(const short8*)&Bl[(waveM + ib*16 + lo)*LDA + ks*32 + quad*8];
            #pragma unroll
            for (int ia = 0; ia < 2; ia++)
                #pragma unroll
                for (int ib = 0; ib < 4; ib++)
                    acc[ia][ib] = __builtin_amdgcn_mfma_f32_16x16x32_bf16(
                        a[ia], bfr[ib], acc[ia][ib], 0, 0, 0);
        }
        __syncthreads();
    }

    #pragma unroll
    for (int ia = 0; ia < 2; ia++) {
        int cb = c0 + waveC + ia*16 + quad*4;
        #pragma unroll
        for (int r = 0; r < 4; r++) {
            size_t rowbase = (size_t)(cb + r)*NPIX;
            #pragma unroll
            for (int ib = 0; ib < 4; ib++) {
                int m = m0 + waveM + ib*16 + lo;
                out[rowbase + m] = acc[ia][ib][r] + feat[rowbase + m];
            }
        }
    }
}

// ---------------------------------------------------------------------------
extern "C" void kernel_launch(void* const* d_in, const int* in_sizes, int n_in,
                              void* d_out, int out_size, void* d_ws, size_t ws_size,
                              hipStream_t stream)
{
    const float* feat = (const float*)d_in[0];
    const float* qw   = (const float*)d_in[1];
    const float* qb   = (const float*)d_in[2];
    const float* kw   = (const float*)d_in[3];
    const float* kb   = (const float*)d_in[4];
    const float* vw   = (const float*)d_in[5];
    const float* vb   = (const float*)d_in[6];
    const float* cw   = (const float*)d_in[7];
    const float* cb   = (const float*)d_in[8];
    float* out = (float*)d_out;
    char* ws = (char*)d_ws;
    char* ws0 = ws;

    unsigned short* Ft  = (unsigned short*)ws;  ws += (size_t)BATCH*NPIX*CH*2;   // 16.78 MB
    unsigned short* Wb  = (unsigned short*)ws;  ws += (size_t)1024*CH*2;         // 1.05 MB
    unsigned short* Qt  = (unsigned short*)ws;  ws += (size_t)BATCH*NPIX*ICH*2;  // 8.39 MB
    unsigned short* Kt  = (unsigned short*)ws;  ws += (size_t)BATCH*NPIX*ICH*2;  // 8.39 MB
    unsigned short* Vt  = (unsigned short*)ws;  ws += (size_t)BATCH*CH*NPIX*2;   // 16.78 MB
    unsigned short* Vp  = (unsigned short*)ws;  ws += (size_t)BATCH*CH*NPIX*2;   // 16.78 MB
    float*         asq  = (float*)ws;           ws += (size_t)BATCH*NPIX*4;
    float*         bsq  = (float*)ws;           ws += (size_t)BATCH*NPIX*4;
    float*         rsum = (float*)ws;           ws += (size_t)BATCH*NPIX*4;
    unsigned short* St  = (unsigned short*)ws;  // nb * 33.55 MB

    const size_t st1 = (size_t)NPIX*NPIX*2;
    const size_t fixed = (size_t)(ws - ws0);
    const int nb = (ws_size >= fixed + (size_t)BATCH*st1) ? BATCH : 1;

    hipMemsetAsync(rsum, 0, (size_t)BATCH*NPIX*sizeof(float), stream);

    prep_w<<<dim3(512), 256, 0, stream>>>(qw, kw, vw, Wb);
    prep_ft<<<dim3(NPIX/64, CH/64, BATCH), 256, 0, stream>>>(feat, Ft);

    conv_mfma<<<dim3(NPIX/128, 8, BATCH), 256, 0, stream>>>(
        Ft, Wb, qb, kb, vb, cw, cb, Qt, Kt, Vt);

    sqb_kernel<<<dim3(NPIX/256, BATCH), 256, 0, stream>>>(Qt, Kt, asq, bsq);

    for (int b0 = 0; b0 < BATCH; b0 += nb) {
        dots_mfma<<<dim3(NPIX/128, NPIX/128, nb), 256, 0, stream>>>(
            Kt, Qt, asq, bsq, St, rsum, b0);
        vscale_kernel<<<dim3(CH*NPIX/(256*8), nb), 256, 0, stream>>>(
            Vt, rsum, Vp, b0);
        pv_mfma<<<dim3(NPIX/128, CH/64, nb), 256, 0, stream>>>(
            Vp, St, feat, out, b0);
    }
}

// Round 7
// 327.308 us; speedup vs baseline: 6.4181x; 1.1784x over previous
//
#include <hip/hip_runtime.h>
#include <math.h>

#define BATCH 4
#define CH    512
#define ICH   256
#define NPIX  4096   // 64*64

typedef short short8 __attribute__((ext_vector_type(8)));
typedef float floatx4 __attribute__((ext_vector_type(4)));

#define BK   64
#define TS   136   // S-tile LDS stride for dots epilogue (272B, 16B-aligned)

static __device__ __forceinline__ unsigned short f2bf(float x) {
    union { float f; unsigned u; } v; v.f = x;
    unsigned r = (v.u + 0x7FFF + ((v.u >> 16) & 1)) >> 16;   // RNE
    return (unsigned short)r;
}
static __device__ __forceinline__ float bf2f(unsigned short u) {
    union { unsigned u; float f; } v; v.u = ((unsigned)u) << 16; return v.f;
}

// async global->LDS, 16B per lane. dst must be wave-uniform; HW adds lane*16.
static __device__ __forceinline__ void gld16(const unsigned short* g, unsigned short* l) {
    __builtin_amdgcn_global_load_lds(
        (const __attribute__((address_space(1))) unsigned int*)g,
        (__attribute__((address_space(3))) unsigned int*)l,
        16, 0, 0);
}

// Swizzled unpadded tile: row r (64 shorts) at LDS r*64; chunk c (8 shorts)
// stored at position c^(r&7). Staging: lane writes dst=wavebase+lane*16, i.e.
// (r = it*32+wid*8+lane/8, pos = lane&7), so it must READ global chunk
// (lane&7)^((lane>>3)&7). Frag read of chunk j, row rr: position j^(rr&7).
#define STAGE_TILE(L, M, row0, RS, k0)                                        \
    {                                                                         \
        int r_  = (it*32) + wid*8 + (lane >> 3);                              \
        int c_  = (lane & 7) ^ ((lane >> 3) & 7);                             \
        gld16(&M[(size_t)((row0) + r_)*(RS) + (k0) + c_*8],                   \
              &L[(it*32 + wid*8)*64]);                                        \
    }

#define FRAG(L, row, ks) \
    (*(const short8*)&L[(row)*64 + (((((ks)<<2) + quad) ^ (lo & 7)) << 3)])

// ---------------------------------------------------------------------------
// prep_w: qw/kw/vw fp32 -> Wb[1024][512] bf16 (rows: 0-255 Q, 256-511 K, 512-1023 V)
// ---------------------------------------------------------------------------
__global__ __launch_bounds__(256)
void prep_w(const float* __restrict__ qw, const float* __restrict__ kw,
            const float* __restrict__ vw, unsigned short* __restrict__ Wb)
{
    int i = (blockIdx.x*256 + threadIdx.x) * 4;
    const float* src;
    int off;
    if (i < 256*512)            { src = qw; off = i; }
    else if (i < 512*512)       { src = kw; off = i - 256*512; }
    else                        { src = vw; off = i - 512*512; }
    float4 f = *(const float4*)&src[off];
    unsigned short pk[4] = { f2bf(f.x), f2bf(f.y), f2bf(f.z), f2bf(f.w) };
    *(uint2*)&Wb[i] = *(uint2*)pk;
}

// ---------------------------------------------------------------------------
// prep_ft: feat [b][c][n] fp32 -> Ft [b][n][c] bf16. grid (64, 8, B).
// ---------------------------------------------------------------------------
__global__ __launch_bounds__(256)
void prep_ft(const float* __restrict__ feat, unsigned short* __restrict__ Ft)
{
    __shared__ unsigned short S[64][65];
    const int t = threadIdx.x;
    const int n0 = blockIdx.x * 64, c0 = blockIdx.y * 64, b = blockIdx.z;

    #pragma unroll
    for (int rep = 0; rep < 4; rep++) {
        int cl = rep*16 + (t >> 4), col4 = (t & 15) * 4;
        float4 f = *(const float4*)&feat[((size_t)b*CH + c0 + cl)*NPIX + n0 + col4];
        S[cl][col4 + 0] = f2bf(f.x);
        S[cl][col4 + 1] = f2bf(f.y);
        S[cl][col4 + 2] = f2bf(f.z);
        S[cl][col4 + 3] = f2bf(f.w);
    }
    __syncthreads();
    #pragma unroll
    for (int rep = 0; rep < 4; rep++) {
        int nn = rep*16 + (t >> 4), cq = t & 15;
        unsigned short h4[4];
        #pragma unroll
        for (int j = 0; j < 4; j++) h4[j] = S[cq*4 + j][nn];
        *(uint2*)&Ft[((size_t)b*NPIX + n0 + nn)*CH + c0 + cq*4] = *(uint2*)h4;
    }
}

// ---------------------------------------------------------------------------
// conv_mfma: fused QKV conv as bf16 MFMA GEMM, K=512, global_load_lds staging.
// yb<2: Q (A=Ft rows n, B=Wq) -> Qt[n][ic]; yb<4: K -> Kt; yb>=4: V -> Vt[c][n]
// grid (32, 8, B); block 256. No min-waves bound (R4: (256,4) spilled AGPRs).
// ---------------------------------------------------------------------------
__global__ __launch_bounds__(256)
void conv_mfma(const unsigned short* __restrict__ Ft,
               const unsigned short* __restrict__ Wb,
               const float* __restrict__ qb, const float* __restrict__ kb,
               const float* __restrict__ vb,
               const float* __restrict__ cw, const float* __restrict__ cb,
               unsigned short* __restrict__ Qt, unsigned short* __restrict__ Kt,
               unsigned short* __restrict__ Vt)
{
    __shared__ unsigned short L0[128*64];   // Ft tile (rows n)
    __shared__ unsigned short L2[128*64];   // W tile  (rows o)

    const int tid = threadIdx.x;
    const int wid = tid >> 6, lane = tid & 63, quad = lane >> 4, lo = lane & 15;
    const int n0 = blockIdx.x * 128;
    const int yb = blockIdx.y;
    const int bz = blockIdx.z;
    const int o_base = yb * 128;
    const int waveA = (wid >> 1) * 64, waveB = (wid & 1) * 64;
    const int is_v = (yb >= 4);
    const size_t fb = (size_t)bz*NPIX;

    floatx4 acc[4][4] = {};

    for (int k0 = 0; k0 < CH; k0 += BK) {
        #pragma unroll
        for (int it = 0; it < 4; it++) {
            STAGE_TILE(L0, Ft, fb + n0, CH, k0);
            STAGE_TILE(L2, Wb, o_base,  CH, k0);
        }
        __syncthreads();
        if (!is_v) {
            #pragma unroll
            for (int ks = 0; ks < 2; ks++) {
                short8 af[4], bw[4];
                #pragma unroll
                for (int i = 0; i < 4; i++) af[i] = FRAG(L0, waveA + i*16 + lo, ks);
                #pragma unroll
                for (int j = 0; j < 4; j++) bw[j] = FRAG(L2, waveB + j*16 + lo, ks);
                #pragma unroll
                for (int i = 0; i < 4; i++)
                    #pragma unroll
                    for (int j = 0; j < 4; j++)
                        acc[i][j] = __builtin_amdgcn_mfma_f32_16x16x32_bf16(af[i], bw[j], acc[i][j], 0, 0, 0);
            }
        } else {
            #pragma unroll
            for (int ks = 0; ks < 2; ks++) {
                short8 aw[4], bf[4];
                #pragma unroll
                for (int i = 0; i < 4; i++) aw[i] = FRAG(L2, waveA + i*16 + lo, ks);
                #pragma unroll
                for (int j = 0; j < 4; j++) bf[j] = FRAG(L0, waveB + j*16 + lo, ks);
                #pragma unroll
                for (int i = 0; i < 4; i++)
                    #pragma unroll
                    for (int j = 0; j < 4; j++)
                        acc[i][j] = __builtin_amdgcn_mfma_f32_16x16x32_bf16(aw[i], bf[j], acc[i][j], 0, 0, 0);
            }
        }
        __syncthreads();
    }

    const float step = 2.0f / 63.0f;
    if (!is_v) {
        unsigned short* Tt = ((yb < 2) ? Qt : Kt) + (size_t)bz*NPIX*ICH;
        const float* bp = (yb < 2) ? qb : kb;
        const int ic_blk = (yb & 1) * 128 + waveB;
        #pragma unroll
        for (int ib = 0; ib < 4; ib++) {
            int ic = ic_blk + ib*16 + lo;
            float bias = bp[ic];
            float cw0 = cw[ic*2+0], cw1 = cw[ic*2+1], cbv = cb[ic];
            #pragma unroll
            for (int ia = 0; ia < 4; ia++) {
                int nb = n0 + waveA + ia*16 + quad*4;
                #pragma unroll
                for (int r = 0; r < 4; r++) {
                    int n = nb + r;
                    float cx = -1.f + (n & 63)*step;
                    float cy = -1.f + (n >> 6)*step;
                    float v = fmaxf(acc[ia][ib][r] + bias, 0.f)
                            + fmaxf(cw0*cx + cw1*cy + cbv, 0.f);
                    Tt[(size_t)n*ICH + ic] = f2bf(v);
                }
            }
        }
    } else {
        const int c_blk = (yb - 4) * 128 + waveA;
        #pragma unroll
        for (int ia = 0; ia < 4; ia++) {
            int cb4 = c_blk + ia*16 + quad*4;
            #pragma unroll
            for (int r = 0; r < 4; r++) {
                int c = cb4 + r;
                float bias = vb[c];
                size_t rowbase = ((size_t)bz*CH + c)*NPIX + n0 + waveB;
                #pragma unroll
                for (int ib = 0; ib < 4; ib++)
                    Vt[rowbase + ib*16 + lo] = f2bf(fmaxf(acc[ia][ib][r] + bias, 0.f));
            }
        }
    }
}

// ---------------------------------------------------------------------------
// asq[n] = |q_n|^2, bsq[n] = |k_n|^2 from bf16 Qt/Kt [n][ic]. grid (16, B).
// ---------------------------------------------------------------------------
__global__ __launch_bounds__(256)
void sqb_kernel(const unsigned short* __restrict__ Qt,
                const unsigned short* __restrict__ Kt,
                float* __restrict__ asq, float* __restrict__ bsq)
{
    int n = blockIdx.x*256 + threadIdx.x;
    int b = blockIdx.y;
    const unsigned short* q = Qt + ((size_t)b*NPIX + n)*ICH;
    const unsigned short* k = Kt + ((size_t)b*NPIX + n)*ICH;
    float qs = 0.f, ks = 0.f;
    #pragma unroll 4
    for (int i = 0; i < ICH/8; i++) {
        uint4 v = *(const uint4*)&q[i*8];
        const unsigned short* s = (const unsigned short*)&v;
        #pragma unroll
        for (int j = 0; j < 8; j++) { float a = bf2f(s[j]); qs += a*a; }
        uint4 w = *(const uint4*)&k[i*8];
        const unsigned short* t = (const unsigned short*)&w;
        #pragma unroll
        for (int j = 0; j < 8; j++) { float a = bf2f(t[j]); ks += a*a; }
    }
    asq[b*NPIX + n] = qs;
    bsq[b*NPIX + n] = ks;
}

// ---------------------------------------------------------------------------
// St[bz][m][n] = exp(-(asq[n]+bsq[m]-2*k_m.q_n)) bf16 + col sums -> rsum[n].
// global_load_lds staging; epilogue stages S-tile in LDS, coalesced 256B rows.
// grid (32, 32, nb); block 256.
// ---------------------------------------------------------------------------
__global__ __launch_bounds__(256)
void dots_mfma(const unsigned short* __restrict__ Kt_,
               const unsigned short* __restrict__ Qt_,
               const float* __restrict__ asq_, const float* __restrict__ bsq_,
               unsigned short* __restrict__ St_, float* __restrict__ rsum_,
               int b0)
{
    __shared__ unsigned short SH[128*TS];   // 34816B; staging uses first 32KB
    unsigned short* Al = SH;                // 128*64
    unsigned short* Bl = SH + 128*64;       // 128*64

    const int tid = threadIdx.x;
    const int wid = tid >> 6, lane = tid & 63, quad = lane >> 4, lo = lane & 15;
    const int m0 = blockIdx.x * 128, n0 = blockIdx.y * 128;
    const int bz = blockIdx.z, gb = b0 + bz;
    const int waveM = (wid >> 1) * 64, waveN = (wid & 1) * 64;

    const unsigned short* Kt = Kt_ + (size_t)gb*NPIX*ICH;
    const unsigned short* Qt = Qt_ + (size_t)gb*NPIX*ICH;
    const float* asq = asq_ + (size_t)gb*NPIX;
    const float* bsq = bsq_ + (size_t)gb*NPIX;
    unsigned short* St = St_ + (size_t)bz*NPIX*NPIX;
    float* rsum = rsum_ + (size_t)gb*NPIX;

    floatx4 acc[4][4] = {};

    for (int k0 = 0; k0 < ICH; k0 += BK) {
        #pragma unroll
        for (int it = 0; it < 4; it++) {
            STAGE_TILE(Al, Kt, m0, ICH, k0);
            STAGE_TILE(Bl, Qt, n0, ICH, k0);
        }
        __syncthreads();
        #pragma unroll
        for (int ks = 0; ks < 2; ks++) {
            short8 a[4], bfr[4];
            #pragma unroll
            for (int im = 0; im < 4; im++) a[im]  = FRAG(Al, waveM + im*16 + lo, ks);
            #pragma unroll
            for (int in = 0; in < 4; in++) bfr[in] = FRAG(Bl, waveN + in*16 + lo, ks);
            #pragma unroll
            for (int im = 0; im < 4; im++)
                #pragma unroll
                for (int in = 0; in < 4; in++)
                    acc[im][in] = __builtin_amdgcn_mfma_f32_16x16x32_bf16(
                        a[im], bfr[in], acc[im][in], 0, 0, 0);
        }
        __syncthreads();
    }

    // epilogue phase 1: exp(-D) -> LDS tile (pair-packed dwords), colsums
    #pragma unroll
    for (int in = 0; in < 4; in++) {
        int nl = waveN + in*16 + lo;
        float aq = asq[n0 + nl];
        float colsum = 0.f;
        #pragma unroll
        for (int im = 0; im < 4; im++) {
            int mb = waveM + im*16 + quad*4;
            #pragma unroll
            for (int r = 0; r < 4; r++) {
                float d = aq + bsq[m0 + mb + r] - 2.f*acc[im][in][r];
                float s = __expf(-d);
                colsum += s;
                unsigned u = (unsigned)f2bf(s);
                unsigned partner = __shfl_xor(u, 1, 64);
                if ((lo & 1) == 0)
                    *(unsigned*)&SH[(mb + r)*TS + nl] = u | (partner << 16);
            }
        }
        colsum += __shfl_xor(colsum, 16, 64);
        colsum += __shfl_xor(colsum, 32, 64);
        if (quad == 0) atomicAdd(&rsum[n0 + nl], colsum);
    }
    __syncthreads();

    // epilogue phase 2: coalesced store, 256B contiguous per row
    #pragma unroll
    for (int it = 0; it < 8; it++) {
        int f = it*256 + tid;
        int row = f >> 4, col = (f & 15) * 8;
        uint4 v = *(const uint4*)&SH[row*TS + col];
        *(uint4*)&St[(size_t)(m0 + row)*NPIX + n0 + col] = v;
    }
}

// ---------------------------------------------------------------------------
// Vp[c][n] = bf16( Vt[c][n] / (rsum[n] + 1e-14) ). grid (1024, nb).
// ---------------------------------------------------------------------------
__global__ __launch_bounds__(256)
void vscale_kernel(const unsigned short* __restrict__ Vt,
                   const float* __restrict__ rsum,
                   unsigned short* __restrict__ Vp, int b0)
{
    int gb = b0 + blockIdx.y;
    size_t base = (size_t)gb*CH*NPIX + ((size_t)blockIdx.x*256 + threadIdx.x) * 8;
    int n = (int)(base & (NPIX - 1));
    const float* rs = rsum + (size_t)gb*NPIX;
    uint4 v = *(const uint4*)&Vt[base];
    const unsigned short* s = (const unsigned short*)&v;
    unsigned short pk[8];
    #pragma unroll
    for (int i = 0; i < 8; i++)
        pk[i] = f2bf(bf2f(s[i]) / (rs[n + i] + 1e-14f));
    *(uint4*)&Vp[base] = *(uint4*)pk;
}

// ---------------------------------------------------------------------------
// out[c][m] = sum_n V'[c][n] * St[m][n] + feat[c][m].
// 128x128 tile, global_load_lds staging. grid (32, 4, nb); block 256.
// ---------------------------------------------------------------------------
__global__ __launch_bounds__(256)
void pv_mfma(const unsigned short* __restrict__ Vp_,
             const unsigned short* __restrict__ St_,
             const float* __restrict__ feat_, float* __restrict__ out_,
             int b0)
{
    __shared__ unsigned short Al[128*64];   // Vp rows c
    __shared__ unsigned short Bl[128*64];   // St rows m
    const int tid = threadIdx.x;
    const int wid = tid >> 6, lane = tid & 63, quad = lane >> 4, lo = lane & 15;
    const int m0 = blockIdx.x * 128, c0 = blockIdx.y * 128;
    const int bz = blockIdx.z, gb = b0 + bz;
    const int waveA = (wid >> 1) * 64, waveB = (wid & 1) * 64;

    const unsigned short* Vp = Vp_ + (size_t)gb*CH*NPIX;
    const unsigned short* St = St_ + (size_t)bz*NPIX*NPIX;
    const float* feat = feat_ + (size_t)gb*CH*NPIX;
    float* out = out_ + (size_t)gb*CH*NPIX;

    floatx4 acc[4][4] = {};

    for (int k0 = 0; k0 < NPIX; k0 += BK) {
        #pragma unroll
        for (int it = 0; it < 4; it++) {
            STAGE_TILE(Al, Vp, c0, NPIX, k0);
            STAGE_TILE(Bl, St, m0, NPIX, k0);
        }
        __syncthreads();
        #pragma unroll
        for (int ks = 0; ks < 2; ks++) {
            short8 a[4], bfr[4];
            #pragma unroll
            for (int ia = 0; ia < 4; ia++) a[ia]  = FRAG(Al, waveA + ia*16 + lo, ks);
            #pragma unroll
            for (int ib = 0; ib < 4; ib++) bfr[ib] = FRAG(Bl, waveB + ib*16 + lo, ks);
            #pragma unroll
            for (int ia = 0; ia < 4; ia++)
                #pragma unroll
                for (int ib = 0; ib < 4; ib++)
                    acc[ia][ib] = __builtin_amdgcn_mfma_f32_16x16x32_bf16(
                        a[ia], bfr[ib], acc[ia][ib], 0, 0, 0);
        }
        __syncthreads();
    }

    #pragma unroll
    for (int ia = 0; ia < 4; ia++) {
        int cb = c0 + waveA + ia*16 + quad*4;
        #pragma unroll
        for (int r = 0; r < 4; r++) {
            size_t rowbase = (size_t)(cb + r)*NPIX;
            #pragma unroll
            for (int ib = 0; ib < 4; ib++) {
                int m = m0 + waveB + ib*16 + lo;
                out[rowbase + m] = acc[ia][ib][r] + feat[rowbase + m];
            }
        }
    }
}

// ---------------------------------------------------------------------------
extern "C" void kernel_launch(void* const* d_in, const int* in_sizes, int n_in,
                              void* d_out, int out_size, void* d_ws, size_t ws_size,
                              hipStream_t stream)
{
    const float* feat = (const float*)d_in[0];
    const float* qw   = (const float*)d_in[1];
    const float* qb   = (const float*)d_in[2];
    const float* kw   = (const float*)d_in[3];
    const float* kb   = (const float*)d_in[4];
    const float* vw   = (const float*)d_in[5];
    const float* vb   = (const float*)d_in[6];
    const float* cw   = (const float*)d_in[7];
    const float* cb   = (const float*)d_in[8];
    float* out = (float*)d_out;
    char* ws = (char*)d_ws;
    char* ws0 = ws;

    unsigned short* Ft  = (unsigned short*)ws;  ws += (size_t)BATCH*NPIX*CH*2;   // 16.78 MB
    unsigned short* Wb  = (unsigned short*)ws;  ws += (size_t)1024*CH*2;         // 1.05 MB
    unsigned short* Qt  = (unsigned short*)ws;  ws += (size_t)BATCH*NPIX*ICH*2;  // 8.39 MB
    unsigned short* Kt  = (unsigned short*)ws;  ws += (size_t)BATCH*NPIX*ICH*2;  // 8.39 MB
    unsigned short* Vt  = (unsigned short*)ws;  ws += (size_t)BATCH*CH*NPIX*2;   // 16.78 MB
    unsigned short* Vp  = (unsigned short*)ws;  ws += (size_t)BATCH*CH*NPIX*2;   // 16.78 MB
    float*         asq  = (float*)ws;           ws += (size_t)BATCH*NPIX*4;
    float*         bsq  = (float*)ws;           ws += (size_t)BATCH*NPIX*4;
    float*         rsum = (float*)ws;           ws += (size_t)BATCH*NPIX*4;
    unsigned short* St  = (unsigned short*)ws;  // nb * 33.55 MB

    const size_t st1 = (size_t)NPIX*NPIX*2;
    const size_t fixed = (size_t)(ws - ws0);
    const int nb = (ws_size >= fixed + (size_t)BATCH*st1) ? BATCH : 1;

    hipMemsetAsync(rsum, 0, (size_t)BATCH*NPIX*sizeof(float), stream);

    prep_w<<<dim3(512), 256, 0, stream>>>(qw, kw, vw, Wb);
    prep_ft<<<dim3(NPIX/64, CH/64, BATCH), 256, 0, stream>>>(feat, Ft);

    conv_mfma<<<dim3(NPIX/128, 8, BATCH), 256, 0, stream>>>(
        Ft, Wb, qb, kb, vb, cw, cb, Qt, Kt, Vt);

    sqb_kernel<<<dim3(NPIX/256, BATCH), 256, 0, stream>>>(Qt, Kt, asq, bsq);

    for (int b0 = 0; b0 < BATCH; b0 += nb) {
        dots_mfma<<<dim3(NPIX/128, NPIX/128, nb), 256, 0, stream>>>(
            Kt, Qt, asq, bsq, St, rsum, b0);
        vscale_kernel<<<dim3(CH*NPIX/(256*8), nb), 256, 0, stream>>>(
            Vt, rsum, Vp, b0);
        pv_mfma<<<dim3(NPIX/128, CH/128, nb), 256, 0, stream>>>(
            Vp, St, feat, out, b0);
    }
}

// Round 8
// 312.847 us; speedup vs baseline: 6.7148x; 1.0462x over previous
//
#include <hip/hip_runtime.h>
#include <math.h>

#define BATCH 4
#define CH    512
#define ICH   256
#define NPIX  4096   // 64*64

typedef short short8 __attribute__((ext_vector_type(8)));
typedef float floatx4 __attribute__((ext_vector_type(4)));

#define BK   64
#define TS   136   // epilogue LDS tile stride (272B rows; <=2-way bank alias)

static __device__ __forceinline__ unsigned short f2bf(float x) {
    union { float f; unsigned u; } v; v.f = x;
    unsigned r = (v.u + 0x7FFF + ((v.u >> 16) & 1)) >> 16;   // RNE
    return (unsigned short)r;
}
static __device__ __forceinline__ float bf2f(unsigned short u) {
    union { unsigned u; float f; } v; v.u = ((unsigned)u) << 16; return v.f;
}
// pack two fp32 (even lane's, odd lane's) to bf16 pair, round-half-up
static __device__ __forceinline__ unsigned pack_bf(unsigned ue, unsigned uo) {
    return ((ue + 0x8000u) >> 16) | ((uo + 0x8000u) & 0xFFFF0000u);
}

// async global->LDS, 16B per lane. dst must be wave-uniform; HW adds lane*16.
static __device__ __forceinline__ void gld16(const unsigned short* g, unsigned short* l) {
    __builtin_amdgcn_global_load_lds(
        (const __attribute__((address_space(1))) unsigned int*)g,
        (__attribute__((address_space(3))) unsigned int*)l,
        16, 0, 0);
}

// Swizzled unpadded tile: row r (64 shorts) at LDS r*64; chunk c at pos c^(r&7).
#define STAGE_TILE(L, M, row0, RS, k0)                                        \
    {                                                                         \
        int r_  = (it*32) + wid*8 + (lane >> 3);                              \
        int c_  = (lane & 7) ^ ((lane >> 3) & 7);                             \
        gld16(&M[(size_t)((row0) + r_)*(RS) + (k0) + c_*8],                   \
              &L[(it*32 + wid*8)*64]);                                        \
    }

#define FRAG(L, row, ks) \
    (*(const short8*)&L[(row)*64 + (((((ks)<<2) + quad) ^ (lo & 7)) << 3)])

// ---------------------------------------------------------------------------
// prep_w: qw/kw/vw fp32 -> Wb[1024][512] bf16 (rows: 0-255 Q, 256-511 K, 512-1023 V)
// ---------------------------------------------------------------------------
__global__ __launch_bounds__(256)
void prep_w(const float* __restrict__ qw, const float* __restrict__ kw,
            const float* __restrict__ vw, unsigned short* __restrict__ Wb)
{
    int i = (blockIdx.x*256 + threadIdx.x) * 4;
    const float* src;
    int off;
    if (i < 256*512)            { src = qw; off = i; }
    else if (i < 512*512)       { src = kw; off = i - 256*512; }
    else                        { src = vw; off = i - 512*512; }
    float4 f = *(const float4*)&src[off];
    unsigned short pk[4] = { f2bf(f.x), f2bf(f.y), f2bf(f.z), f2bf(f.w) };
    *(uint2*)&Wb[i] = *(uint2*)pk;
}

// ---------------------------------------------------------------------------
// prep_ft: feat [b][c][n] fp32 -> Ft [b][n][c] bf16. grid (64, 8, B).
// ---------------------------------------------------------------------------
__global__ __launch_bounds__(256)
void prep_ft(const float* __restrict__ feat, unsigned short* __restrict__ Ft)
{
    __shared__ unsigned short S[64][65];
    const int t = threadIdx.x;
    const int n0 = blockIdx.x * 64, c0 = blockIdx.y * 64, b = blockIdx.z;

    #pragma unroll
    for (int rep = 0; rep < 4; rep++) {
        int cl = rep*16 + (t >> 4), col4 = (t & 15) * 4;
        float4 f = *(const float4*)&feat[((size_t)b*CH + c0 + cl)*NPIX + n0 + col4];
        S[cl][col4 + 0] = f2bf(f.x);
        S[cl][col4 + 1] = f2bf(f.y);
        S[cl][col4 + 2] = f2bf(f.z);
        S[cl][col4 + 3] = f2bf(f.w);
    }
    __syncthreads();
    #pragma unroll
    for (int rep = 0; rep < 4; rep++) {
        int nn = rep*16 + (t >> 4), cq = t & 15;
        unsigned short h4[4];
        #pragma unroll
        for (int j = 0; j < 4; j++) h4[j] = S[cq*4 + j][nn];
        *(uint2*)&Ft[((size_t)b*NPIX + n0 + nn)*CH + c0 + cq*4] = *(uint2*)h4;
    }
}

// ---------------------------------------------------------------------------
// conv_mfma: fused QKV conv as bf16 MFMA GEMM, K=512, global_load_lds staging.
// Epilogue goes through an LDS tile (reusing staging space) -> coalesced
// dwordx4 stores (R7 had 64 scattered 2B stores/lane).
// grid (32, 8, B); block 256. No min-waves bound (R4: (256,4) spilled AGPRs).
// ---------------------------------------------------------------------------
__global__ __launch_bounds__(256)
void conv_mfma(const unsigned short* __restrict__ Ft,
               const unsigned short* __restrict__ Wb,
               const float* __restrict__ qb, const float* __restrict__ kb,
               const float* __restrict__ vb,
               const float* __restrict__ cw, const float* __restrict__ cb,
               unsigned short* __restrict__ Qt, unsigned short* __restrict__ Kt,
               unsigned short* __restrict__ Vt)
{
    __shared__ unsigned short SH[128*TS];   // 34816B; staging uses first 32KB
    unsigned short* L0 = SH;                // Ft tile (rows n), 128*64
    unsigned short* L2 = SH + 128*64;       // W tile (rows o), 128*64

    const int tid = threadIdx.x;
    const int wid = tid >> 6, lane = tid & 63, quad = lane >> 4, lo = lane & 15;
    const int n0 = blockIdx.x * 128;
    const int yb = blockIdx.y;
    const int bz = blockIdx.z;
    const int o_base = yb * 128;
    const int waveA = (wid >> 1) * 64, waveB = (wid & 1) * 64;
    const int is_v = (yb >= 4);
    const size_t fb = (size_t)bz*NPIX;

    floatx4 acc[4][4] = {};

    for (int k0 = 0; k0 < CH; k0 += BK) {
        #pragma unroll
        for (int it = 0; it < 4; it++) {
            STAGE_TILE(L0, Ft, fb + n0, CH, k0);
            STAGE_TILE(L2, Wb, o_base,  CH, k0);
        }
        __syncthreads();
        if (!is_v) {
            #pragma unroll
            for (int ks = 0; ks < 2; ks++) {
                short8 af[4], bw[4];
                #pragma unroll
                for (int i = 0; i < 4; i++) af[i] = FRAG(L0, waveA + i*16 + lo, ks);
                #pragma unroll
                for (int j = 0; j < 4; j++) bw[j] = FRAG(L2, waveB + j*16 + lo, ks);
                #pragma unroll
                for (int i = 0; i < 4; i++)
                    #pragma unroll
                    for (int j = 0; j < 4; j++)
                        acc[i][j] = __builtin_amdgcn_mfma_f32_16x16x32_bf16(af[i], bw[j], acc[i][j], 0, 0, 0);
            }
        } else {
            #pragma unroll
            for (int ks = 0; ks < 2; ks++) {
                short8 aw[4], bf[4];
                #pragma unroll
                for (int i = 0; i < 4; i++) aw[i] = FRAG(L2, waveA + i*16 + lo, ks);
                #pragma unroll
                for (int j = 0; j < 4; j++) bf[j] = FRAG(L0, waveB + j*16 + lo, ks);
                #pragma unroll
                for (int i = 0; i < 4; i++)
                    #pragma unroll
                    for (int j = 0; j < 4; j++)
                        acc[i][j] = __builtin_amdgcn_mfma_f32_16x16x32_bf16(aw[i], bf[j], acc[i][j], 0, 0, 0);
            }
        }
        __syncthreads();
    }

    // epilogue phase 1: values -> LDS tile [row 128][col 128], pair-packed dwords.
    // Q/K: row = n (local), col = ic (local).  V: row = c (local), col = n (local).
    const float step = 2.0f / 63.0f;
    if (!is_v) {
        const float* bp = (yb < 2) ? qb : kb;
        const int icg0 = (yb & 1) * 128;
        #pragma unroll
        for (int ib = 0; ib < 4; ib++) {
            int colL = waveB + ib*16 + lo;
            int ic = icg0 + colL;
            float bias = bp[ic];
            float cw0 = cw[ic*2+0], cw1 = cw[ic*2+1], cbv = cb[ic];
            #pragma unroll
            for (int ia = 0; ia < 4; ia++) {
                int rowL = waveA + ia*16 + quad*4;
                #pragma unroll
                for (int r = 0; r < 4; r++) {
                    int n = n0 + rowL + r;
                    float cx = -1.f + (n & 63)*step;
                    float cy = -1.f + (n >> 6)*step;
                    float v = fmaxf(acc[ia][ib][r] + bias, 0.f)
                            + fmaxf(cw0*cx + cw1*cy + cbv, 0.f);
                    unsigned u = __float_as_uint(v);
                    unsigned p = __shfl_xor(u, 1, 64);
                    if ((lo & 1) == 0)
                        *(unsigned*)&SH[(rowL + r)*TS + colL] = pack_bf(u, p);
                }
            }
        }
    } else {
        const int c_blk0 = (yb - 4) * 128;
        #pragma unroll
        for (int ia = 0; ia < 4; ia++) {
            int rowL = waveA + ia*16 + quad*4;
            #pragma unroll
            for (int r = 0; r < 4; r++) {
                float bias = vb[c_blk0 + rowL + r];
                #pragma unroll
                for (int ib = 0; ib < 4; ib++) {
                    int colL = waveB + ib*16 + lo;
                    float v = fmaxf(acc[ia][ib][r] + bias, 0.f);
                    unsigned u = __float_as_uint(v);
                    unsigned p = __shfl_xor(u, 1, 64);
                    if ((lo & 1) == 0)
                        *(unsigned*)&SH[(rowL + r)*TS + colL] = pack_bf(u, p);
                }
            }
        }
    }
    __syncthreads();

    // epilogue phase 2: coalesced copy to global (256B per row segment)
    unsigned short* dstp;
    int row0, rs, col0;
    if (!is_v) { dstp = ((yb < 2) ? Qt : Kt) + (size_t)bz*NPIX*ICH;
                 row0 = n0; rs = ICH; col0 = (yb & 1) * 128; }
    else       { dstp = Vt + (size_t)bz*CH*NPIX;
                 row0 = (yb - 4) * 128; rs = NPIX; col0 = n0; }
    #pragma unroll
    for (int it = 0; it < 8; it++) {
        int f = it*256 + tid;
        int row = f >> 4, col = (f & 15) * 8;
        uint4 v = *(const uint4*)&SH[row*TS + col];
        *(uint4*)&dstp[(size_t)(row0 + row)*rs + col0 + col] = v;
    }
}

// ---------------------------------------------------------------------------
// asq[n] = |q_n|^2, bsq[n] = |k_n|^2 from bf16 Qt/Kt [n][ic]. grid (16, B).
// ---------------------------------------------------------------------------
__global__ __launch_bounds__(256)
void sqb_kernel(const unsigned short* __restrict__ Qt,
                const unsigned short* __restrict__ Kt,
                float* __restrict__ asq, float* __restrict__ bsq)
{
    int n = blockIdx.x*256 + threadIdx.x;
    int b = blockIdx.y;
    const unsigned short* q = Qt + ((size_t)b*NPIX + n)*ICH;
    const unsigned short* k = Kt + ((size_t)b*NPIX + n)*ICH;
    float qs = 0.f, ks = 0.f;
    #pragma unroll 4
    for (int i = 0; i < ICH/8; i++) {
        uint4 v = *(const uint4*)&q[i*8];
        const unsigned short* s = (const unsigned short*)&v;
        #pragma unroll
        for (int j = 0; j < 8; j++) { float a = bf2f(s[j]); qs += a*a; }
        uint4 w = *(const uint4*)&k[i*8];
        const unsigned short* t = (const unsigned short*)&w;
        #pragma unroll
        for (int j = 0; j < 8; j++) { float a = bf2f(t[j]); ks += a*a; }
    }
    asq[b*NPIX + n] = qs;
    bsq[b*NPIX + n] = ks;
}

// ---------------------------------------------------------------------------
// St[bz][m][n] = exp(-(asq[n]+bsq[m]-2*k_m.q_n)) bf16 + col sums -> rsum[n].
// grid (32, 32, nb); block 256.
// ---------------------------------------------------------------------------
__global__ __launch_bounds__(256)
void dots_mfma(const unsigned short* __restrict__ Kt_,
               const unsigned short* __restrict__ Qt_,
               const float* __restrict__ asq_, const float* __restrict__ bsq_,
               unsigned short* __restrict__ St_, float* __restrict__ rsum_,
               int b0)
{
    __shared__ unsigned short SH[128*TS];   // 34816B; staging uses first 32KB
    unsigned short* Al = SH;                // 128*64
    unsigned short* Bl = SH + 128*64;       // 128*64

    const int tid = threadIdx.x;
    const int wid = tid >> 6, lane = tid & 63, quad = lane >> 4, lo = lane & 15;
    const int m0 = blockIdx.x * 128, n0 = blockIdx.y * 128;
    const int bz = blockIdx.z, gb = b0 + bz;
    const int waveM = (wid >> 1) * 64, waveN = (wid & 1) * 64;

    const unsigned short* Kt = Kt_ + (size_t)gb*NPIX*ICH;
    const unsigned short* Qt = Qt_ + (size_t)gb*NPIX*ICH;
    const float* asq = asq_ + (size_t)gb*NPIX;
    const float* bsq = bsq_ + (size_t)gb*NPIX;
    unsigned short* St = St_ + (size_t)bz*NPIX*NPIX;
    float* rsum = rsum_ + (size_t)gb*NPIX;

    floatx4 acc[4][4] = {};

    for (int k0 = 0; k0 < ICH; k0 += BK) {
        #pragma unroll
        for (int it = 0; it < 4; it++) {
            STAGE_TILE(Al, Kt, m0, ICH, k0);
            STAGE_TILE(Bl, Qt, n0, ICH, k0);
        }
        __syncthreads();
        #pragma unroll
        for (int ks = 0; ks < 2; ks++) {
            short8 a[4], bfr[4];
            #pragma unroll
            for (int im = 0; im < 4; im++) a[im]  = FRAG(Al, waveM + im*16 + lo, ks);
            #pragma unroll
            for (int in = 0; in < 4; in++) bfr[in] = FRAG(Bl, waveN + in*16 + lo, ks);
            #pragma unroll
            for (int im = 0; im < 4; im++)
                #pragma unroll
                for (int in = 0; in < 4; in++)
                    acc[im][in] = __builtin_amdgcn_mfma_f32_16x16x32_bf16(
                        a[im], bfr[in], acc[im][in], 0, 0, 0);
        }
        __syncthreads();
    }

    // epilogue phase 1: exp(-D) -> LDS tile (cheap pair-pack), colsums
    #pragma unroll
    for (int in = 0; in < 4; in++) {
        int nl = waveN + in*16 + lo;
        float aq = asq[n0 + nl];
        float colsum = 0.f;
        #pragma unroll
        for (int im = 0; im < 4; im++) {
            int mb = waveM + im*16 + quad*4;
            #pragma unroll
            for (int r = 0; r < 4; r++) {
                float d = aq + bsq[m0 + mb + r] - 2.f*acc[im][in][r];
                float s = __expf(-d);
                colsum += s;
                unsigned u = __float_as_uint(s);
                unsigned p = __shfl_xor(u, 1, 64);
                if ((lo & 1) == 0)
                    *(unsigned*)&SH[(mb + r)*TS + nl] = pack_bf(u, p);
            }
        }
        colsum += __shfl_xor(colsum, 16, 64);
        colsum += __shfl_xor(colsum, 32, 64);
        if (quad == 0) atomicAdd(&rsum[n0 + nl], colsum);
    }
    __syncthreads();

    // epilogue phase 2: coalesced store, 256B contiguous per row
    #pragma unroll
    for (int it = 0; it < 8; it++) {
        int f = it*256 + tid;
        int row = f >> 4, col = (f & 15) * 8;
        uint4 v = *(const uint4*)&SH[row*TS + col];
        *(uint4*)&St[(size_t)(m0 + row)*NPIX + n0 + col] = v;
    }
}

// ---------------------------------------------------------------------------
// Vp[c][n] = bf16( Vt[c][n] / (rsum[n] + 1e-14) ). grid (1024, nb).
// ---------------------------------------------------------------------------
__global__ __launch_bounds__(256)
void vscale_kernel(const unsigned short* __restrict__ Vt,
                   const float* __restrict__ rsum,
                   unsigned short* __restrict__ Vp, int b0)
{
    int gb = b0 + blockIdx.y;
    size_t base = (size_t)gb*CH*NPIX + ((size_t)blockIdx.x*256 + threadIdx.x) * 8;
    int n = (int)(base & (NPIX - 1));
    const float* rs = rsum + (size_t)gb*NPIX;
    uint4 v = *(const uint4*)&Vt[base];
    const unsigned short* s = (const unsigned short*)&v;
    unsigned short pk[8];
    #pragma unroll
    for (int i = 0; i < 8; i++)
        pk[i] = f2bf(bf2f(s[i]) / (rs[n + i] + 1e-14f));
    *(uint4*)&Vp[base] = *(uint4*)pk;
}

// ---------------------------------------------------------------------------
// out[c][m] = sum_n V'[c][n] * St[m][n] + feat[c][m].
// 128x128 tile, global_load_lds staging. grid (32, 4, nb); block 256.
// ---------------------------------------------------------------------------
__global__ __launch_bounds__(256)
void pv_mfma(const unsigned short* __restrict__ Vp_,
             const unsigned short* __restrict__ St_,
             const float* __restrict__ feat_, float* __restrict__ out_,
             int b0)
{
    __shared__ unsigned short Al[128*64];   // Vp rows c
    __shared__ unsigned short Bl[128*64];   // St rows m
    const int tid = threadIdx.x;
    const int wid = tid >> 6, lane = tid & 63, quad = lane >> 4, lo = lane & 15;
    const int m0 = blockIdx.x * 128, c0 = blockIdx.y * 128;
    const int bz = blockIdx.z, gb = b0 + bz;
    const int waveA = (wid >> 1) * 64, waveB = (wid & 1) * 64;

    const unsigned short* Vp = Vp_ + (size_t)gb*CH*NPIX;
    const unsigned short* St = St_ + (size_t)bz*NPIX*NPIX;
    const float* feat = feat_ + (size_t)gb*CH*NPIX;
    float* out = out_ + (size_t)gb*CH*NPIX;

    floatx4 acc[4][4] = {};

    for (int k0 = 0; k0 < NPIX; k0 += BK) {
        #pragma unroll
        for (int it = 0; it < 4; it++) {
            STAGE_TILE(Al, Vp, c0, NPIX, k0);
            STAGE_TILE(Bl, St, m0, NPIX, k0);
        }
        __syncthreads();
        #pragma unroll
        for (int ks = 0; ks < 2; ks++) {
            short8 a[4], bfr[4];
            #pragma unroll
            for (int ia = 0; ia < 4; ia++) a[ia]  = FRAG(Al, waveA + ia*16 + lo, ks);
            #pragma unroll
            for (int ib = 0; ib < 4; ib++) bfr[ib] = FRAG(Bl, waveB + ib*16 + lo, ks);
            #pragma unroll
            for (int ia = 0; ia < 4; ia++)
                #pragma unroll
                for (int ib = 0; ib < 4; ib++)
                    acc[ia][ib] = __builtin_amdgcn_mfma_f32_16x16x32_bf16(
                        a[ia], bfr[ib], acc[ia][ib], 0, 0, 0);
        }
        __syncthreads();
    }

    #pragma unroll
    for (int ia = 0; ia < 4; ia++) {
        int cb = c0 + waveA + ia*16 + quad*4;
        #pragma unroll
        for (int r = 0; r < 4; r++) {
            size_t rowbase = (size_t)(cb + r)*NPIX;
            #pragma unroll
            for (int ib = 0; ib < 4; ib++) {
                int m = m0 + waveB + ib*16 + lo;
                out[rowbase + m] = acc[ia][ib][r] + feat[rowbase + m];
            }
        }
    }
}

// ---------------------------------------------------------------------------
extern "C" void kernel_launch(void* const* d_in, const int* in_sizes, int n_in,
                              void* d_out, int out_size, void* d_ws, size_t ws_size,
                              hipStream_t stream)
{
    const float* feat = (const float*)d_in[0];
    const float* qw   = (const float*)d_in[1];
    const float* qb   = (const float*)d_in[2];
    const float* kw   = (const float*)d_in[3];
    const float* kb   = (const float*)d_in[4];
    const float* vw   = (const float*)d_in[5];
    const float* vb   = (const float*)d_in[6];
    const float* cw   = (const float*)d_in[7];
    const float* cb   = (const float*)d_in[8];
    float* out = (float*)d_out;
    char* ws = (char*)d_ws;
    char* ws0 = ws;

    unsigned short* Ft  = (unsigned short*)ws;  ws += (size_t)BATCH*NPIX*CH*2;   // 16.78 MB
    unsigned short* Wb  = (unsigned short*)ws;  ws += (size_t)1024*CH*2;         // 1.05 MB
    unsigned short* Qt  = (unsigned short*)ws;  ws += (size_t)BATCH*NPIX*ICH*2;  // 8.39 MB
    unsigned short* Kt  = (unsigned short*)ws;  ws += (size_t)BATCH*NPIX*ICH*2;  // 8.39 MB
    unsigned short* Vt  = (unsigned short*)ws;  ws += (size_t)BATCH*CH*NPIX*2;   // 16.78 MB
    unsigned short* Vp  = (unsigned short*)ws;  ws += (size_t)BATCH*CH*NPIX*2;   // 16.78 MB
    float*         asq  = (float*)ws;           ws += (size_t)BATCH*NPIX*4;
    float*         bsq  = (float*)ws;           ws += (size_t)BATCH*NPIX*4;
    float*         rsum = (float*)ws;           ws += (size_t)BATCH*NPIX*4;
    unsigned short* St  = (unsigned short*)ws;  // nb * 33.55 MB

    const size_t st1 = (size_t)NPIX*NPIX*2;
    const size_t fixed = (size_t)(ws - ws0);
    const int nb = (ws_size >= fixed + (size_t)BATCH*st1) ? BATCH : 1;

    hipMemsetAsync(rsum, 0, (size_t)BATCH*NPIX*sizeof(float), stream);

    prep_w<<<dim3(512), 256, 0, stream>>>(qw, kw, vw, Wb);
    prep_ft<<<dim3(NPIX/64, CH/64, BATCH), 256, 0, stream>>>(feat, Ft);

    conv_mfma<<<dim3(NPIX/128, 8, BATCH), 256, 0, stream>>>(
        Ft, Wb, qb, kb, vb, cw, cb, Qt, Kt, Vt);

    sqb_kernel<<<dim3(NPIX/256, BATCH), 256, 0, stream>>>(Qt, Kt, asq, bsq);

    for (int b0 = 0; b0 < BATCH; b0 += nb) {
        dots_mfma<<<dim3(NPIX/128, NPIX/128, nb), 256, 0, stream>>>(
            Kt, Qt, asq, bsq, St, rsum, b0);
        vscale_kernel<<<dim3(CH*NPIX/(256*8), nb), 256, 0, stream>>>(
            Vt, rsum, Vp, b0);
        pv_mfma<<<dim3(NPIX/128, CH/128, nb), 256, 0, stream>>>(
            Vp, St, feat, out, b0);
    }
}